// Round 12
// baseline (256.177 us; speedup 1.0000x reference)
//
#include <hip/hip_runtime.h>

#define BQ 4
#define SQ 2048
#define DQ 1024
#define HQ 16
#define BHQ 64

typedef __attribute__((ext_vector_type(8))) short short8;
typedef __attribute__((ext_vector_type(4))) float f32x4;
typedef __attribute__((ext_vector_type(16))) float f32x16;
typedef unsigned short u16;
typedef unsigned int u32;
typedef unsigned long long u64;

__device__ __forceinline__ u16 f2bf(float f) {
  u32 u = __float_as_uint(f);
  u32 r = u + 0x7fffu + ((u >> 16) & 1u);
  return (u16)(r >> 16);
}
__device__ __forceinline__ float bf2f(u16 h) {
  return __uint_as_float(((u32)h) << 16);
}

// packed f32x2 -> bf16x2 (RNE), one instruction
__device__ __forceinline__ u32 pkbf(float lo, float hi_) {
  u32 r;
  asm("v_cvt_pk_bf16_f32 %0, %1, %2" : "=v"(r) : "v"(lo), "v"(hi_));
  return r;
}
// raw v_exp_f32: computes 2^x (input already in log2 domain)
__device__ __forceinline__ float fexp2(float x) {
  float r;
  asm("v_exp_f32 %0, %1" : "=v"(r) : "v"(x));
  return r;
}
// cross-half exchange via shfl (known-correct)
__device__ __forceinline__ float xmax32(float x) { return fmaxf(x, __shfl_xor(x, 32)); }
__device__ __forceinline__ float xsum32(float x) { return x + __shfl_xor(x, 32); }
__device__ __forceinline__ u32 xword(u32 send) { return (u32)__shfl_xor((int)send, 32); }

// async global->LDS, 16B per lane. LDS dest must be wave-uniform; HW adds lane*16.
__device__ __forceinline__ void gload_lds16(const void* g, void* l) {
  __builtin_amdgcn_global_load_lds(
      (const __attribute__((address_space(1))) u32*)(unsigned long long)g,
      (__attribute__((address_space(3))) u32*)(u32)(unsigned long long)l,
      16, 0, 0);
}

// ---------------- fp32 -> bf16 convert (vectorized) ----------------
__global__ __launch_bounds__(256) void k_cvt(const float* __restrict__ in, u16* __restrict__ out, int n4) {
  int i = blockIdx.x * 256 + threadIdx.x;
  if (i < n4) {
    float4 v = ((const float4*)in)[i];
    ushort4 o;
    o.x = f2bf(v.x); o.y = f2bf(v.y); o.z = f2bf(v.z); o.w = f2bf(v.w);
    ((ushort4*)out)[i] = o;
  }
}

// ---------------- transpose + convert: in[R][C] f32 -> out[C][R] bf16 ----------------
__global__ __launch_bounds__(256) void k_transpose_cvt(const float* __restrict__ in, u16* __restrict__ out,
                                                       int R, int C) {
  __shared__ float t[32][33];
  int c0 = blockIdx.x * 32, r0 = blockIdx.y * 32;
  int tx = threadIdx.x & 31, ty = threadIdx.x >> 5;
  for (int rr = ty; rr < 32; rr += 8)
    t[rr][tx] = in[(size_t)(r0 + rr) * C + c0 + tx];
  __syncthreads();
  for (int rr = ty; rr < 32; rr += 8)
    out[(size_t)(c0 + rr) * R + r0 + tx] = f2bf(t[tx][rr]);
}

// ---------------- RoPE cos/sin table [S][32][2] f32 ----------------
__global__ __launch_bounds__(256) void k_rope_table(float* __restrict__ tab) {
  int i = blockIdx.x * 256 + threadIdx.x;
  if (i >= SQ * 32) return;
  int s = i >> 5, dp = i & 31;
  float invf = expf(-0.28782313662425576f * (float)dp);
  float ang = (float)s * invf;
  tab[i * 2] = cosf(ang);
  tab[i * 2 + 1] = sinf(ang);
}

// ---------------- mask all-ones bitmask per batch: mbits[b] bit c = chunk c all-ones ----------------
__global__ __launch_bounds__(256) void k_mflags(const int* __restrict__ mask, u64* __restrict__ mbits) {
  int tid = threadIdx.x;  // 4 waves; wave = batch, lane = 32-chunk
  int b = tid >> 6, c = tid & 63;
  int all1 = 1;
  for (int i = 0; i < 32; ++i) all1 &= (mask[b * SQ + c * 32 + i] != 0) ? 1 : 0;
  u64 m = __ballot(all1);
  if (c == 0) mbits[b] = m;
}

// ---------------- GEMM: C[M,N] = A[M,K](bf16) @ Bt[N,K]^T(bf16) ----------------
// EPI 0: write f32 C row-major. EPI 1 (QKV): fused epilogue —
//   q/k: RoPE applied in f32 (pairs acc[nf], acc[nf+2] = dims d, d+32), q scaled 0.125*log2e.
//   v: written directly to tiled slot-swizzled vTs [bh][kt][64 d][32 k].
template <int EPI>
__global__ __launch_bounds__(256) void k_gemm(const u16* __restrict__ A, const u16* __restrict__ Bt,
                                              float* __restrict__ Cf, u16* __restrict__ qb,
                                              u16* __restrict__ kb, u16* __restrict__ vTs,
                                              const float* __restrict__ tab, int K) {
  __shared__ u16 lA[128 * 32];
  __shared__ u16 lB[128 * 32];
  int tid = threadIdx.x, w = tid >> 6, l = tid & 63;
  int wm = w >> 1, wn = w & 1;
  int tm = blockIdx.x, tn = blockIdx.y;
  int li = l & 15, lg = l >> 4;
  const u16* gA = A + (size_t)tm * 128 * K;
  const u16* gB = Bt + (size_t)tn * 128 * K;
  f32x4 acc[4][4];
#pragma unroll
  for (int i = 0; i < 4; i++)
#pragma unroll
    for (int j = 0; j < 4; j++) acc[i][j] = (f32x4){0.f, 0.f, 0.f, 0.f};
  int c0 = w, c1 = w + 4;
  int srow0 = c0 * 16 + (l >> 2), srow1 = c1 * 16 + (l >> 2);
  int scol = (l & 3) * 8;
  for (int kt = 0; kt < K; kt += 32) {
    __syncthreads();
    gload_lds16(gA + (size_t)srow0 * K + kt + scol, &lA[c0 * 512]);
    gload_lds16(gA + (size_t)srow1 * K + kt + scol, &lA[c1 * 512]);
    gload_lds16(gB + (size_t)srow0 * K + kt + scol, &lB[c0 * 512]);
    gload_lds16(gB + (size_t)srow1 * K + kt + scol, &lB[c1 * 512]);
    __syncthreads();
    short8 af[4], bfr[4];
#pragma unroll
    for (int mf = 0; mf < 4; ++mf) af[mf] = *(const short8*)&lA[(wm * 64 + mf * 16 + li) * 32 + lg * 8];
#pragma unroll
    for (int nf = 0; nf < 4; ++nf) bfr[nf] = *(const short8*)&lB[(wn * 64 + nf * 16 + li) * 32 + lg * 8];
#pragma unroll
    for (int mf = 0; mf < 4; ++mf)
#pragma unroll
      for (int nf = 0; nf < 4; ++nf)
        acc[mf][nf] = __builtin_amdgcn_mfma_f32_16x16x32_bf16(af[mf], bfr[nf], acc[mf][nf], 0, 0, 0);
  }
  if (EPI == 0) {
#pragma unroll
    for (int mf = 0; mf < 4; ++mf) {
      int mg0 = tm * 128 + wm * 64 + mf * 16 + lg * 4;
#pragma unroll
      for (int nf = 0; nf < 4; ++nf) {
        int ng = tn * 128 + wn * 64 + nf * 16 + li;
#pragma unroll
        for (int r = 0; r < 4; ++r)
          Cf[(size_t)(mg0 + r) * 1024 + ng] = acc[mf][nf][r];
      }
    }
  } else {
    int which = tn >> 3;                 // 0=q 1=k 2=v (128-col tiles, 8 per matrix)
    int h = (tn & 7) * 2 + wn;           // head
#pragma unroll
    for (int mf = 0; mf < 4; ++mf) {
#pragma unroll
      for (int r = 0; r < 4; ++r) {
        int mg = tm * 128 + wm * 64 + mf * 16 + lg * 4 + r;
        int b = mg >> 11, s = mg & 2047;
        if (which < 2) {
          float scale = (which == 0) ? 0.125f * 1.44269504088896f : 1.0f;
          u16* dst = (which == 0 ? qb : kb) + ((((size_t)b * HQ + h) * SQ + s) << 6);
#pragma unroll
          for (int nf2 = 0; nf2 < 2; ++nf2) {
            int dp = nf2 * 16 + li;      // 0..31
            float c = tab[(s * 32 + dp) * 2];
            float sn = tab[(s * 32 + dp) * 2 + 1];
            float a = acc[mf][nf2][r];
            float bb = acc[mf][nf2 + 2][r];
            dst[dp] = f2bf((a * c - bb * sn) * scale);
            dst[dp + 32] = f2bf((bb * c + a * sn) * scale);
          }
        } else {
          int kt = s >> 5, kk = s & 31;
          size_t tb = (((size_t)(b * HQ + h) * 64 + kt) * 64);
#pragma unroll
          for (int nf = 0; nf < 4; ++nf) {
            int d = nf * 16 + li;
            int addr = (((kk >> 3) ^ ((d >> 1) & 3)) << 3) + (kk & 7);
            vTs[(tb + d) * 32 + addr] = f2bf(acc[mf][nf][r]);
          }
        }
      }
    }
  }
}

// ---------------- flash v11: 2-wave blocks + in-block split-K (uniform ~33 trips/wave) ----------------
// 2048 blocks (bh, u): q-tiles qa=u, qb=63-u share one staging sweep over tiles [0,qb].
// wave0: qb over [0,33). wave1: qa complete over [0,qa] (epilogue mid-loop, state reset),
// then qb over [33,qb]. qb partials merged via LDS: O = O0*2^(m0-m) + O1*2^(m1-m).
// Staging/compute layouts byte-identical to the verified flash7 (source-swizzled K,
// pre-swizzled tiled V). 8 blocks/CU (LDS 16KB each).
__global__ __launch_bounds__(128) void k_flash11(const u16* __restrict__ Q, const u16* __restrict__ Kb,
                                                 const u16* __restrict__ VTs, const int* __restrict__ mask,
                                                 const u64* __restrict__ mbits, u16* __restrict__ O) {
  __shared__ alignas(16) u16 Kl[2][2048];
  __shared__ alignas(16) u16 Vl[2][2048];
  int bid = blockIdx.x;
  int bh = bid & 63;
  int u = bid >> 6;          // 0..31
  int qa = u, qb = 63 - u;   // qb in [32,63]
  int tid = threadIdx.x, w = tid >> 6, l = tid & 63;
  int j = l & 31, hi = l >> 5;
  int b = bh >> 4, h = bh & 15;
  const int* mp = mask + b * SQ + 4 * hi;
  u64 mb = mbits[b];
  int swK = j & 7, swV = (j >> 1) & 3;

  // staging: 128 threads, 2 gload_lds16 per wave per K/V tile-half.
  // K LDS layout [32 rows][64 u16], row r slot s holds global slot s^(r&7) (flash7 layout).
  const u16* KgA = Kb + ((size_t)bh * SQ + (w * 16 + (l >> 3))) * 64 + (((l & 7) ^ (l >> 3)) * 8);
  const u16* VgA = VTs + (size_t)bh * 64 * 2048 + (size_t)(w * 128 + l) * 8;

  f32x16 o0, o1;
  float mrun, lrun;
  short8 qf[4];

  auto resetst = [&]() {
#pragma unroll
    for (int i = 0; i < 16; ++i) { o0[i] = 0.f; o1[i] = 0.f; }
    mrun = -INFINITY; lrun = 0.f;
  };
  auto loadq = [&](int qt) {
    const u16* qp = Q + ((size_t)bh * SQ + qt * 32 + j) * 64 + hi * 8;
#pragma unroll
    for (int kb2 = 0; kb2 < 4; ++kb2) qf[kb2] = *(const short8*)(qp + kb2 * 16);
  };
  auto stage = [&](int kt, int buf) {
    u16* kb_ = &Kl[buf][w * 1024];
    u16* vb_ = &Vl[buf][w * 1024];
    const u16* kg = KgA + (size_t)kt * 2048;
    const u16* vg = VgA + (size_t)kt * 2048;
    gload_lds16(kg, kb_);
    gload_lds16(kg + 512, kb_ + 512);
    gload_lds16(vg, vb_);
    gload_lds16(vg + 512, vb_ + 512);
  };

  auto compute = [&](int kt, int tgt) {
    const u16* Kc = Kl[kt & 1];
    const u16* Vc = Vl[kt & 1];
    short8 kcf[4];
#pragma unroll
    for (int kb2 = 0; kb2 < 4; ++kb2)
      kcf[kb2] = *(const short8*)&Kc[j * 64 + (((hi + 2 * kb2)) ^ swK) * 8];

    f32x16 s;
#pragma unroll
    for (int i = 0; i < 16; ++i) s[i] = 0.f;
    __builtin_amdgcn_s_setprio(1);
#pragma unroll
    for (int kb2 = 0; kb2 < 4; ++kb2)
      s = __builtin_amdgcn_mfma_f32_32x32x16_bf16(kcf[kb2], qf[kb2], s, 0, 0, 0);
    __builtin_amdgcn_s_setprio(0);

    short8 va0 = *(const short8*)&Vc[j * 32 + ((hi) ^ swV) * 8];
    short8 va1 = *(const short8*)&Vc[j * 32 + ((hi + 2) ^ swV) * 8];
    short8 vb0 = *(const short8*)&Vc[(j + 32) * 32 + ((hi) ^ swV) * 8];
    short8 vb1 = *(const short8*)&Vc[(j + 32) * 32 + ((hi + 2) ^ swV) * 8];

    if (!((mb >> kt) & 1ull)) {
#pragma unroll
      for (int rq = 0; rq < 4; ++rq) {
        int4 mv = *(const int4*)(mp + kt * 32 + 8 * rq);
        if (!mv.x) s[4 * rq + 0] = -INFINITY;
        if (!mv.y) s[4 * rq + 1] = -INFINITY;
        if (!mv.z) s[4 * rq + 2] = -INFINITY;
        if (!mv.w) s[4 * rq + 3] = -INFINITY;
      }
    }
    if (kt == tgt) {  // diagonal tile
#pragma unroll
      for (int rq = 0; rq < 4; ++rq)
#pragma unroll
        for (int t = 0; t < 4; ++t)
          if (8 * rq + 4 * hi + t > j) s[4 * rq + t] = -INFINITY;
    }

    float t0 = fmaxf(fmaxf(fmaxf(s[0], s[1]), fmaxf(s[2], s[3])),
                     fmaxf(fmaxf(s[4], s[5]), fmaxf(s[6], s[7])));
    t0 = fmaxf(t0, fmaxf(fmaxf(fmaxf(s[8], s[9]), fmaxf(s[10], s[11])),
                         fmaxf(fmaxf(s[12], s[13]), fmaxf(s[14], s[15]))));
    if (!__all(t0 <= mrun + 8.0f)) {  // defer-max (T13)
      float tm2 = xmax32(t0);
      float mn = fmaxf(fmaxf(mrun, tm2), -1e30f);
      float alpha = fexp2(mrun - mn);
      mrun = mn;
      lrun *= alpha;
#pragma unroll
      for (int i = 0; i < 16; ++i) { o0[i] *= alpha; o1[i] *= alpha; }
    }
    float ts = 0.f;
#pragma unroll
    for (int i = 0; i < 16; ++i) {
      float pv = fexp2(s[i] - mrun);
      s[i] = pv;
      ts += pv;
    }
    lrun += ts;

    u32 pa[4], pb[4];
#pragma unroll
    for (int q2 = 0; q2 < 4; ++q2) {
      pa[q2] = pkbf(s[4 * q2 + 0], s[4 * q2 + 1]);
      pb[q2] = pkbf(s[4 * q2 + 2], s[4 * q2 + 3]);
    }
    u32 ya01 = xword(hi ? pa[0] : pa[1]);
    u32 yb01 = xword(hi ? pb[0] : pb[1]);
    u32 ya23 = xword(hi ? pa[2] : pa[3]);
    u32 yb23 = xword(hi ? pb[2] : pb[3]);
    union { short8 s8; u32 wd[4]; } f0, f1;
    f0.wd[0] = hi ? ya01 : pa[0];
    f0.wd[1] = hi ? yb01 : pb[0];
    f0.wd[2] = hi ? pa[1] : ya01;
    f0.wd[3] = hi ? pb[1] : yb01;
    f1.wd[0] = hi ? ya23 : pa[2];
    f1.wd[1] = hi ? yb23 : pb[2];
    f1.wd[2] = hi ? pa[3] : ya23;
    f1.wd[3] = hi ? pb[3] : yb23;

    __builtin_amdgcn_s_setprio(1);
    o0 = __builtin_amdgcn_mfma_f32_32x32x16_bf16(va0, f0.s8, o0, 0, 0, 0);
    o0 = __builtin_amdgcn_mfma_f32_32x32x16_bf16(va1, f1.s8, o0, 0, 0, 0);
    o1 = __builtin_amdgcn_mfma_f32_32x32x16_bf16(vb0, f0.s8, o1, 0, 0, 0);
    o1 = __builtin_amdgcn_mfma_f32_32x32x16_bf16(vb1, f1.s8, o1, 0, 0, 0);
    __builtin_amdgcn_s_setprio(0);
  };

  auto epilogue = [&](int qt) {
    float lfull = xsum32(lrun);
    float inv = 1.0f / lfull;
    u16* ob = O + ((size_t)b * SQ + qt * 32 + j) * DQ + h * 64 + 4 * hi;
#pragma unroll
    for (int q2 = 0; q2 < 4; ++q2) {
#pragma unroll
      for (int e = 0; e < 2; ++e) {
        *(u32*)(ob + 8 * q2 + 2 * e) = pkbf(o0[4 * q2 + 2 * e] * inv, o0[4 * q2 + 2 * e + 1] * inv);
        *(u32*)(ob + 32 + 8 * q2 + 2 * e) = pkbf(o1[4 * q2 + 2 * e] * inv, o1[4 * q2 + 2 * e + 1] * inv);
      }
    }
  };

  int W0END = (qb < 33) ? qb + 1 : 33;
  resetst();
  loadq(w == 0 ? qb : qa);
  stage(0, 0);
  __syncthreads();

  for (int kt = 0; kt <= qb; ++kt) {
    if (kt < qb) stage(kt + 1, (kt + 1) & 1);
    if (w == 0) {
      if (kt < W0END) compute(kt, qb);
    } else {
      if (kt <= qa) {
        compute(kt, qa);
        if (kt == qa) {
          epilogue(qa);
          if (qb >= 33) { resetst(); loadq(qb); }
        }
      } else if (kt >= 33 && qb >= 33) {
        compute(kt, qb);
      }
    }
    __syncthreads();
  }

  if (qb >= 33) {
    float* Ob = (float*)&Kl[0][0];    // 8KB: 64 lanes x 32 f32
    float* MLb = (float*)&Vl[0][0];   // 512B: 64 lanes x (m,l)
    if (w == 0) {
#pragma unroll
      for (int i = 0; i < 16; ++i) { Ob[l * 32 + i] = o0[i]; Ob[l * 32 + 16 + i] = o1[i]; }
      MLb[l * 2] = mrun;
      MLb[l * 2 + 1] = lrun;
    }
    __syncthreads();
    if (w == 1) {
      float m0 = MLb[l * 2], l0 = MLb[l * 2 + 1];
      float m = fmaxf(mrun, m0);
      float a1 = fexp2(mrun - m), a0 = fexp2(m0 - m);
#pragma unroll
      for (int i = 0; i < 16; ++i) {
        o0[i] = o0[i] * a1 + Ob[l * 32 + i] * a0;
        o1[i] = o1[i] * a1 + Ob[l * 32 + 16 + i] * a0;
      }
      lrun = lrun * a1 + l0 * a0;
      epilogue(qb);
    }
  } else {
    if (w == 0) epilogue(qb);
  }
}

extern "C" void kernel_launch(void* const* d_in, const int* in_sizes, int n_in,
                              void* d_out, int out_size, void* d_ws, size_t ws_size,
                              hipStream_t stream) {
  const float* x = (const float*)d_in[0];
  const int* mask = (const int*)d_in[1];
  const float* wqkv = (const float*)d_in[2];
  const float* wout = (const float*)d_in[3];
  float* out = (float*)d_out;
  char* ws = (char*)d_ws;

  u16* xb    = (u16*)(ws + 0);           // 16 MB
  u16* wqkvT = (u16*)(ws + 16777216);    // 6 MB  [3072][1024]
  u16* woutT = (u16*)(ws + 23068672);    // 2 MB  [1024][1024]
  u16* qbuf  = (u16*)(ws + 25165824);    // 16 MB [bh][S][64]
  u16* kbuf  = (u16*)(ws + 41943040);    // 16 MB
  u16* vTs   = (u16*)(ws + 75497472);    // 16 MB [bh][64 kt][64][32] slot-swizzled
  u16* attnb = (u16*)(ws + 92274688);    // 16 MB [B*S][1024]
  float* tab = (float*)(ws + 109051904); // 512 KB
  u64* mbits = (u64*)(ws + 109576192);   // 32 B

  k_rope_table<<<256, 256, 0, stream>>>(tab);
  k_mflags<<<1, 256, 0, stream>>>(mask, mbits);
  k_cvt<<<8192, 256, 0, stream>>>(x, xb, 2097152);
  k_transpose_cvt<<<dim3(96, 32), 256, 0, stream>>>(wqkv, wqkvT, 1024, 3072);
  k_transpose_cvt<<<dim3(32, 32), 256, 0, stream>>>(wout, woutT, 1024, 1024);
  k_gemm<1><<<dim3(64, 24), 256, 0, stream>>>(xb, wqkvT, nullptr, qbuf, kbuf, vTs, tab, 1024);
  k_flash11<<<2048, 128, 0, stream>>>(qbuf, kbuf, vTs, mask, mbits, attnb);
  k_gemm<0><<<dim3(64, 8), 256, 0, stream>>>(attnb, woutT, out, nullptr, nullptr, nullptr, nullptr, 1024);
}

// Round 13
// 220.946 us; speedup vs baseline: 1.1595x; 1.1595x over previous
//
#include <hip/hip_runtime.h>

#define BQ 4
#define SQ 2048
#define DQ 1024
#define HQ 16
#define BHQ 64

typedef __attribute__((ext_vector_type(8))) short short8;
typedef __attribute__((ext_vector_type(4))) float f32x4;
typedef __attribute__((ext_vector_type(16))) float f32x16;
typedef unsigned short u16;
typedef unsigned int u32;
typedef unsigned long long u64;

__device__ __forceinline__ u16 f2bf(float f) {
  u32 u = __float_as_uint(f);
  u32 r = u + 0x7fffu + ((u >> 16) & 1u);
  return (u16)(r >> 16);
}
__device__ __forceinline__ float bf2f(u16 h) {
  return __uint_as_float(((u32)h) << 16);
}

// packed f32x2 -> bf16x2 (RNE), one instruction
__device__ __forceinline__ u32 pkbf(float lo, float hi_) {
  u32 r;
  asm("v_cvt_pk_bf16_f32 %0, %1, %2" : "=v"(r) : "v"(lo), "v"(hi_));
  return r;
}
// raw v_exp_f32: computes 2^x (input already in log2 domain)
__device__ __forceinline__ float fexp2(float x) {
  float r;
  asm("v_exp_f32 %0, %1" : "=v"(r) : "v"(x));
  return r;
}
// cross-half exchange via shfl (known-correct)
__device__ __forceinline__ float xmax32(float x) { return fmaxf(x, __shfl_xor(x, 32)); }
__device__ __forceinline__ float xsum32(float x) { return x + __shfl_xor(x, 32); }
__device__ __forceinline__ u32 xword(u32 send) { return (u32)__shfl_xor((int)send, 32); }

// async global->LDS, 16B per lane. LDS dest must be wave-uniform; HW adds lane*16.
__device__ __forceinline__ void gload_lds16(const void* g, void* l) {
  __builtin_amdgcn_global_load_lds(
      (const __attribute__((address_space(1))) u32*)(unsigned long long)g,
      (__attribute__((address_space(3))) u32*)(u32)(unsigned long long)l,
      16, 0, 0);
}

// ---------------- fp32 -> bf16 convert (vectorized) ----------------
__global__ __launch_bounds__(256) void k_cvt(const float* __restrict__ in, u16* __restrict__ out, int n4) {
  int i = blockIdx.x * 256 + threadIdx.x;
  if (i < n4) {
    float4 v = ((const float4*)in)[i];
    ushort4 o;
    o.x = f2bf(v.x); o.y = f2bf(v.y); o.z = f2bf(v.z); o.w = f2bf(v.w);
    ((ushort4*)out)[i] = o;
  }
}

// ---------------- transpose + convert: in[R][C] f32 -> out[C][R] bf16 ----------------
__global__ __launch_bounds__(256) void k_transpose_cvt(const float* __restrict__ in, u16* __restrict__ out,
                                                       int R, int C) {
  __shared__ float t[32][33];
  int c0 = blockIdx.x * 32, r0 = blockIdx.y * 32;
  int tx = threadIdx.x & 31, ty = threadIdx.x >> 5;
  for (int rr = ty; rr < 32; rr += 8)
    t[rr][tx] = in[(size_t)(r0 + rr) * C + c0 + tx];
  __syncthreads();
  for (int rr = ty; rr < 32; rr += 8)
    out[(size_t)(c0 + rr) * R + r0 + tx] = f2bf(t[tx][rr]);
}

// ---------------- RoPE cos/sin table [S][32][2] f32 ----------------
__global__ __launch_bounds__(256) void k_rope_table(float* __restrict__ tab) {
  int i = blockIdx.x * 256 + threadIdx.x;
  if (i >= SQ * 32) return;
  int s = i >> 5, dp = i & 31;
  float invf = expf(-0.28782313662425576f * (float)dp);
  float ang = (float)s * invf;
  tab[i * 2] = cosf(ang);
  tab[i * 2 + 1] = sinf(ang);
}

// ---------------- mask all-ones bitmask per batch: mbits[b] bit c = chunk c all-ones ----------------
__global__ __launch_bounds__(256) void k_mflags(const int* __restrict__ mask, u64* __restrict__ mbits) {
  int tid = threadIdx.x;  // 4 waves; wave = batch, lane = 32-chunk
  int b = tid >> 6, c = tid & 63;
  int all1 = 1;
  for (int i = 0; i < 32; ++i) all1 &= (mask[b * SQ + c * 32 + i] != 0) ? 1 : 0;
  u64 m = __ballot(all1);
  if (c == 0) mbits[b] = m;
}

// ---------------- GEMM: C[M,N] = A[M,K](bf16) @ Bt[N,K]^T(bf16) ----------------
// BK=64, K-swizzled LDS (flash7 pattern): LDS row = 64 u16 (128B, 8 slots of 16B);
// LDS (row, slot) holds global slot (slot ^ (row&7)) -> ds_read_b128 2-way conflict (free).
// EPI 0: write f32 C row-major. EPI 1 (QKV): fused epilogue —
//   q/k: RoPE applied in f32 (pairs acc[nf], acc[nf+2] = dims d, d+32), q scaled 0.125*log2e.
//   v: written directly to tiled slot-swizzled vTs [bh][kt][64 d][32 k].
template <int EPI>
__global__ __launch_bounds__(256) void k_gemm(const u16* __restrict__ A, const u16* __restrict__ Bt,
                                              float* __restrict__ Cf, u16* __restrict__ qb,
                                              u16* __restrict__ kb, u16* __restrict__ vTs,
                                              const float* __restrict__ tab, int K) {
  __shared__ u16 lA[128 * 64];
  __shared__ u16 lB[128 * 64];
  int tid = threadIdx.x, w = tid >> 6, l = tid & 63;
  int wm = w >> 1, wn = w & 1;
  int tm = blockIdx.x, tn = blockIdx.y;
  int li = l & 15, lg = l >> 4;
  const u16* gA = A + (size_t)tm * 128 * K;
  const u16* gB = Bt + (size_t)tn * 128 * K;
  f32x4 acc[4][4];
#pragma unroll
  for (int i = 0; i < 4; i++)
#pragma unroll
    for (int j = 0; j < 4; j++) acc[i][j] = (f32x4){0.f, 0.f, 0.f, 0.f};

  // staging geometry: per instr, wave covers chunk = i*4+w (8 rows x 128B = 1KB);
  // lane l -> row-in-chunk lr = l>>3, slot = l&7; source slot = slot ^ (row&7) (row&7 == lr).
  int lr = l >> 3, lslot = l & 7;
  int scol = ((lslot ^ lr) * 8);

  for (int kt = 0; kt < K; kt += 64) {
    __syncthreads();
#pragma unroll
    for (int i = 0; i < 4; ++i) {
      int ch = i * 4 + w;
      int row = ch * 8 + lr;
      gload_lds16(gA + (size_t)row * K + kt + scol, &lA[ch * 512]);
      gload_lds16(gB + (size_t)row * K + kt + scol, &lB[ch * 512]);
    }
    __syncthreads();
#pragma unroll
    for (int kk = 0; kk < 2; ++kk) {
      short8 af[4], bfr[4];
#pragma unroll
      for (int mf = 0; mf < 4; ++mf) {
        int row = wm * 64 + mf * 16 + li;
        af[mf] = *(const short8*)&lA[row * 64 + (((kk * 4 + lg)) ^ (row & 7)) * 8];
      }
#pragma unroll
      for (int nf = 0; nf < 4; ++nf) {
        int row = wn * 64 + nf * 16 + li;
        bfr[nf] = *(const short8*)&lB[row * 64 + (((kk * 4 + lg)) ^ (row & 7)) * 8];
      }
#pragma unroll
      for (int mf = 0; mf < 4; ++mf)
#pragma unroll
        for (int nf = 0; nf < 4; ++nf)
          acc[mf][nf] = __builtin_amdgcn_mfma_f32_16x16x32_bf16(af[mf], bfr[nf], acc[mf][nf], 0, 0, 0);
    }
  }
  if (EPI == 0) {
#pragma unroll
    for (int mf = 0; mf < 4; ++mf) {
      int mg0 = tm * 128 + wm * 64 + mf * 16 + lg * 4;
#pragma unroll
      for (int nf = 0; nf < 4; ++nf) {
        int ng = tn * 128 + wn * 64 + nf * 16 + li;
#pragma unroll
        for (int r = 0; r < 4; ++r)
          Cf[(size_t)(mg0 + r) * 1024 + ng] = acc[mf][nf][r];
      }
    }
  } else {
    int which = tn >> 3;                 // 0=q 1=k 2=v (128-col tiles, 8 per matrix)
    int h = (tn & 7) * 2 + wn;           // head
#pragma unroll
    for (int mf = 0; mf < 4; ++mf) {
#pragma unroll
      for (int r = 0; r < 4; ++r) {
        int mg = tm * 128 + wm * 64 + mf * 16 + lg * 4 + r;
        int b = mg >> 11, s = mg & 2047;
        if (which < 2) {
          float scale = (which == 0) ? 0.125f * 1.44269504088896f : 1.0f;
          u16* dst = (which == 0 ? qb : kb) + ((((size_t)b * HQ + h) * SQ + s) << 6);
#pragma unroll
          for (int nf2 = 0; nf2 < 2; ++nf2) {
            int dp = nf2 * 16 + li;      // 0..31
            float c = tab[(s * 32 + dp) * 2];
            float sn = tab[(s * 32 + dp) * 2 + 1];
            float a = acc[mf][nf2][r];
            float bb = acc[mf][nf2 + 2][r];
            dst[dp] = f2bf((a * c - bb * sn) * scale);
            dst[dp + 32] = f2bf((bb * c + a * sn) * scale);
          }
        } else {
          int kt = s >> 5, kk = s & 31;
          size_t tb = (((size_t)(b * HQ + h) * 64 + kt) * 64);
#pragma unroll
          for (int nf = 0; nf < 4; ++nf) {
            int d = nf * 16 + li;
            int addr = (((kk >> 3) ^ ((d >> 1) & 3)) << 3) + (kk & 7);
            vTs[(tb + d) * 32 + addr] = f2bf(acc[mf][nf][r]);
          }
        }
      }
    }
  }
}

// ---------------- flash attention v7 (93us verified): LDS-shared K/V, swapped QK^T ----------------
// Block = 4 waves on q-tiles {qsup*4 .. qsup*4+3} of ONE bh. Per k-tile the block stages
// K (4KB, source-swizzled) + V^T (4KB, pre-swizzled tiled layout) via global_load_lds,
// double-buffered, one barrier per tile. CU-balanced qsup quad {v,7-v,8+v,15-v} (sum 30).
__global__ __launch_bounds__(256) void k_flash7(const u16* __restrict__ Q, const u16* __restrict__ Kb,
                                                const u16* __restrict__ VTs, const int* __restrict__ mask,
                                                const u64* __restrict__ mbits, u16* __restrict__ O) {
  __shared__ alignas(16) u16 Kl[2][2048];
  __shared__ alignas(16) u16 Vl[2][2048];
  int bid = blockIdx.x;
  int bh = bid & 63;
  int u = bid >> 6, v = u & 3, k4 = u >> 2;
  int qsup = (k4 == 0) ? v : (k4 == 1) ? 7 - v : (k4 == 2) ? 8 + v : 15 - v;
  int tid = threadIdx.x, w = tid >> 6, l = tid & 63;
  int j = l & 31, hi = l >> 5;
  int myqt = qsup * 4 + w;
  int nt = qsup * 4 + 4;
  int b = bh >> 4, h = bh & 15;
  const int* mp = mask + b * SQ + 4 * hi;
  u64 mb = mbits[b];

  // staging source addresses (per-thread)
  int sr = tid >> 3, sc16 = tid & 7;
  const u16* Kg0 = Kb + ((size_t)bh * SQ) * 64 + sr * 64 + ((sc16 ^ (sr & 7)) * 8);  // + kt*2048
  const u16* Vg0 = VTs + ((size_t)bh * 64) * 2048 + tid * 8;                          // + kt*2048
  u16* KlB = &Kl[0][(size_t)w * 512];  // wave-uniform dest bases (buffer toggled by +2048 u16)
  u16* VlB = &Vl[0][(size_t)w * 512];

  // Q fragments (B operand)
  int qbase = myqt * 32;
  const u16* qp = Q + ((size_t)bh * SQ + qbase + j) * 64 + hi * 8;
  short8 qf[4];
#pragma unroll
  for (int kb = 0; kb < 4; ++kb) qf[kb] = *(const short8*)(qp + kb * 16);

  f32x16 o0, o1;
#pragma unroll
  for (int i = 0; i < 16; ++i) { o0[i] = 0.f; o1[i] = 0.f; }
  float mrun = -INFINITY, lrun = 0.f;

  int swK = (j & 7), swV = (j >> 1) & 3;

  // prologue: stage tile 0 into buffer 0
  gload_lds16(Kg0, KlB);
  gload_lds16(Vg0, VlB);
  __syncthreads();

  for (int kt = 0; kt < nt; ++kt) {
    int cur = kt & 1;
    if (kt + 1 < nt) {  // stage next tile into other buffer
      gload_lds16(Kg0 + (size_t)(kt + 1) * 2048, KlB + (cur ^ 1) * 2048);
      gload_lds16(Vg0 + (size_t)(kt + 1) * 2048, VlB + (cur ^ 1) * 2048);
    }

    const u16* Kc = Kl[cur];
    const u16* Vc = Vl[cur];

    short8 kcf[4];
#pragma unroll
    for (int kb = 0; kb < 4; ++kb)
      kcf[kb] = *(const short8*)&Kc[j * 64 + (((hi + 2 * kb)) ^ swK) * 8];

    f32x16 s;
#pragma unroll
    for (int i = 0; i < 16; ++i) s[i] = 0.f;
    __builtin_amdgcn_s_setprio(1);
#pragma unroll
    for (int kb = 0; kb < 4; ++kb)
      s = __builtin_amdgcn_mfma_f32_32x32x16_bf16(kcf[kb], qf[kb], s, 0, 0, 0);
    __builtin_amdgcn_s_setprio(0);

    // V fragments for this tile (LDS; scheduled early by compiler)
    short8 va0 = *(const short8*)&Vc[j * 32 + ((hi) ^ swV) * 8];
    short8 va1 = *(const short8*)&Vc[j * 32 + ((hi + 2) ^ swV) * 8];
    short8 vb0 = *(const short8*)&Vc[(j + 32) * 32 + ((hi) ^ swV) * 8];
    short8 vb1 = *(const short8*)&Vc[(j + 32) * 32 + ((hi + 2) ^ swV) * 8];

    // pad mask: only when this 32-chunk has zeros (never in this harness)
    if (!((mb >> kt) & 1ull)) {
#pragma unroll
      for (int rq = 0; rq < 4; ++rq) {
        int4 mv = *(const int4*)(mp + kt * 32 + 8 * rq);
        if (!mv.x) s[4 * rq + 0] = -INFINITY;
        if (!mv.y) s[4 * rq + 1] = -INFINITY;
        if (!mv.z) s[4 * rq + 2] = -INFINITY;
        if (!mv.w) s[4 * rq + 3] = -INFINITY;
      }
    }
    // causal: diagonal tile masks k>q; tiles beyond own diagonal are fully masked
    if (kt >= myqt) {
      if (kt > myqt) {
#pragma unroll
        for (int i = 0; i < 16; ++i) s[i] = -INFINITY;
      } else {
#pragma unroll
        for (int rq = 0; rq < 4; ++rq)
#pragma unroll
          for (int t = 0; t < 4; ++t)
            if (8 * rq + 4 * hi + t > j) s[4 * rq + t] = -INFINITY;
      }
    }

    // online softmax in log2 domain, fully in-register
    float t0 = fmaxf(fmaxf(fmaxf(s[0], s[1]), fmaxf(s[2], s[3])),
                     fmaxf(fmaxf(s[4], s[5]), fmaxf(s[6], s[7])));
    t0 = fmaxf(t0, fmaxf(fmaxf(fmaxf(s[8], s[9]), fmaxf(s[10], s[11])),
                         fmaxf(fmaxf(s[12], s[13]), fmaxf(s[14], s[15]))));
    if (!__all(t0 <= mrun + 8.0f)) {  // defer-max (T13)
      float tm2 = xmax32(t0);
      float mn = fmaxf(fmaxf(mrun, tm2), -1e30f);
      float alpha = fexp2(mrun - mn);
      mrun = mn;
      lrun *= alpha;
#pragma unroll
      for (int i = 0; i < 16; ++i) { o0[i] *= alpha; o1[i] *= alpha; }
    }
    float ts = 0.f;
#pragma unroll
    for (int i = 0; i < 16; ++i) {
      float pv = fexp2(s[i] - mrun);
      s[i] = pv;
      ts += pv;
    }
    lrun += ts;

    // pack P^T into B fragments: cvt_pk pairs + one cross-half shfl per word-pair
    u32 pa[4], pb[4];
#pragma unroll
    for (int q2 = 0; q2 < 4; ++q2) {
      pa[q2] = pkbf(s[4 * q2 + 0], s[4 * q2 + 1]);
      pb[q2] = pkbf(s[4 * q2 + 2], s[4 * q2 + 3]);
    }
    u32 ya01 = xword(hi ? pa[0] : pa[1]);
    u32 yb01 = xword(hi ? pb[0] : pb[1]);
    u32 ya23 = xword(hi ? pa[2] : pa[3]);
    u32 yb23 = xword(hi ? pb[2] : pb[3]);
    union { short8 s8; u32 wd[4]; } f0, f1;
    f0.wd[0] = hi ? ya01 : pa[0];
    f0.wd[1] = hi ? yb01 : pb[0];
    f0.wd[2] = hi ? pa[1] : ya01;
    f0.wd[3] = hi ? pb[1] : yb01;
    f1.wd[0] = hi ? ya23 : pa[2];
    f1.wd[1] = hi ? yb23 : pb[2];
    f1.wd[2] = hi ? pa[3] : ya23;
    f1.wd[3] = hi ? pb[3] : yb23;

    // PV: O^T += V^T(frag A) x P^T(frag B)
    __builtin_amdgcn_s_setprio(1);
    o0 = __builtin_amdgcn_mfma_f32_32x32x16_bf16(va0, f0.s8, o0, 0, 0, 0);
    o0 = __builtin_amdgcn_mfma_f32_32x32x16_bf16(va1, f1.s8, o0, 0, 0, 0);
    o1 = __builtin_amdgcn_mfma_f32_32x32x16_bf16(vb0, f0.s8, o1, 0, 0, 0);
    o1 = __builtin_amdgcn_mfma_f32_32x32x16_bf16(vb1, f1.s8, o1, 0, 0, 0);
    __builtin_amdgcn_s_setprio(0);

    __syncthreads();  // drains vmem (next stage) + all waves done reading cur
  }

  // epilogue: merge the two halves' lrun, store q rows
  float lfull = xsum32(lrun);
  float inv = 1.0f / lfull;
  u16* ob = O + ((size_t)b * SQ + qbase + j) * DQ + h * 64 + 4 * hi;
#pragma unroll
  for (int q2 = 0; q2 < 4; ++q2) {
#pragma unroll
    for (int e = 0; e < 2; ++e) {
      *(u32*)(ob + 8 * q2 + 2 * e) = pkbf(o0[4 * q2 + 2 * e] * inv, o0[4 * q2 + 2 * e + 1] * inv);
      *(u32*)(ob + 32 + 8 * q2 + 2 * e) = pkbf(o1[4 * q2 + 2 * e] * inv, o1[4 * q2 + 2 * e + 1] * inv);
    }
  }
}

extern "C" void kernel_launch(void* const* d_in, const int* in_sizes, int n_in,
                              void* d_out, int out_size, void* d_ws, size_t ws_size,
                              hipStream_t stream) {
  const float* x = (const float*)d_in[0];
  const int* mask = (const int*)d_in[1];
  const float* wqkv = (const float*)d_in[2];
  const float* wout = (const float*)d_in[3];
  float* out = (float*)d_out;
  char* ws = (char*)d_ws;

  u16* xb    = (u16*)(ws + 0);           // 16 MB
  u16* wqkvT = (u16*)(ws + 16777216);    // 6 MB  [3072][1024]
  u16* woutT = (u16*)(ws + 23068672);    // 2 MB  [1024][1024]
  u16* qbuf  = (u16*)(ws + 25165824);    // 16 MB [bh][S][64]
  u16* kbuf  = (u16*)(ws + 41943040);    // 16 MB
  u16* vTs   = (u16*)(ws + 75497472);    // 16 MB [bh][64 kt][64][32] slot-swizzled
  u16* attnb = (u16*)(ws + 92274688);    // 16 MB [B*S][1024]
  float* tab = (float*)(ws + 109051904); // 512 KB
  u64* mbits = (u64*)(ws + 109576192);   // 32 B

  k_rope_table<<<256, 256, 0, stream>>>(tab);
  k_mflags<<<1, 256, 0, stream>>>(mask, mbits);
  k_cvt<<<8192, 256, 0, stream>>>(x, xb, 2097152);
  k_transpose_cvt<<<dim3(96, 32), 256, 0, stream>>>(wqkv, wqkvT, 1024, 3072);
  k_transpose_cvt<<<dim3(32, 32), 256, 0, stream>>>(wout, woutT, 1024, 1024);
  k_gemm<1><<<dim3(64, 24), 256, 0, stream>>>(xb, wqkvT, nullptr, qbuf, kbuf, vTs, tab, 1024);
  k_flash7<<<1024, 256, 0, stream>>>(qbuf, kbuf, vTs, mask, mbits, attnb);
  k_gemm<0><<<dim3(64, 8), 256, 0, stream>>>(attnb, woutT, out, nullptr, nullptr, nullptr, nullptr, 1024);
}

// Round 14
// 198.227 us; speedup vs baseline: 1.2923x; 1.1146x over previous
//
#include <hip/hip_runtime.h>

#define BQ 4
#define SQ 2048
#define DQ 1024
#define HQ 16
#define BHQ 64

typedef __attribute__((ext_vector_type(8))) short short8;
typedef __attribute__((ext_vector_type(4))) float f32x4;
typedef __attribute__((ext_vector_type(16))) float f32x16;
typedef __attribute__((ext_vector_type(2))) unsigned int u32x2;
typedef unsigned short u16;
typedef unsigned int u32;
typedef unsigned long long u64;

__device__ __forceinline__ u16 f2bf(float f) {
  u32 u = __float_as_uint(f);
  u32 r = u + 0x7fffu + ((u >> 16) & 1u);
  return (u16)(r >> 16);
}
__device__ __forceinline__ float bf2f(u16 h) {
  return __uint_as_float(((u32)h) << 16);
}

// packed f32x2 -> bf16x2 (RNE), one instruction
__device__ __forceinline__ u32 pkbf(float lo, float hi_) {
  u32 r;
  asm("v_cvt_pk_bf16_f32 %0, %1, %2" : "=v"(r) : "v"(lo), "v"(hi_));
  return r;
}
// raw v_exp_f32: computes 2^x (input already in log2 domain)
__device__ __forceinline__ float fexp2(float x) {
  float r;
  asm("v_exp_f32 %0, %1" : "=v"(r) : "v"(x));
  return r;
}
// cross-half exchange via shfl (known-correct)
__device__ __forceinline__ float xmax32(float x) { return fmaxf(x, __shfl_xor(x, 32)); }
__device__ __forceinline__ float xsum32(float x) { return x + __shfl_xor(x, 32); }
__device__ __forceinline__ u32 xword(u32 send) { return (u32)__shfl_xor((int)send, 32); }

// async global->LDS, 16B per lane. LDS dest must be wave-uniform; HW adds lane*16.
__device__ __forceinline__ void gload_lds16(const void* g, void* l) {
  __builtin_amdgcn_global_load_lds(
      (const __attribute__((address_space(1))) u32*)(unsigned long long)g,
      (__attribute__((address_space(3))) u32*)(u32)(unsigned long long)l,
      16, 0, 0);
}

// ---------------- fp32 -> bf16 convert (vectorized) ----------------
__global__ __launch_bounds__(256) void k_cvt(const float* __restrict__ in, u16* __restrict__ out, int n4) {
  int i = blockIdx.x * 256 + threadIdx.x;
  if (i < n4) {
    float4 v = ((const float4*)in)[i];
    ushort4 o;
    o.x = f2bf(v.x); o.y = f2bf(v.y); o.z = f2bf(v.z); o.w = f2bf(v.w);
    ((ushort4*)out)[i] = o;
  }
}

// ---------------- transpose + convert: in[R][C] f32 -> out[C][R] bf16 ----------------
__global__ __launch_bounds__(256) void k_transpose_cvt(const float* __restrict__ in, u16* __restrict__ out,
                                                       int R, int C) {
  __shared__ float t[32][33];
  int c0 = blockIdx.x * 32, r0 = blockIdx.y * 32;
  int tx = threadIdx.x & 31, ty = threadIdx.x >> 5;
  for (int rr = ty; rr < 32; rr += 8)
    t[rr][tx] = in[(size_t)(r0 + rr) * C + c0 + tx];
  __syncthreads();
  for (int rr = ty; rr < 32; rr += 8)
    out[(size_t)(c0 + rr) * R + r0 + tx] = f2bf(t[tx][rr]);
}

// ---------------- RoPE cos/sin table [S][32][2] f32 ----------------
__global__ __launch_bounds__(256) void k_rope_table(float* __restrict__ tab) {
  int i = blockIdx.x * 256 + threadIdx.x;
  if (i >= SQ * 32) return;
  int s = i >> 5, dp = i & 31;
  float invf = expf(-0.28782313662425576f * (float)dp);
  float ang = (float)s * invf;
  tab[i * 2] = cosf(ang);
  tab[i * 2 + 1] = sinf(ang);
}

// ---------------- mask all-ones bitmask per batch: mbits[b] bit c = chunk c all-ones ----------------
__global__ __launch_bounds__(256) void k_mflags(const int* __restrict__ mask, u64* __restrict__ mbits) {
  int tid = threadIdx.x;  // 4 waves; wave = batch, lane = 32-chunk
  int b = tid >> 6, c = tid & 63;
  int all1 = 1;
  for (int i = 0; i < 32; ++i) all1 &= (mask[b * SQ + c * 32 + i] != 0) ? 1 : 0;
  u64 m = __ballot(all1);
  if (c == 0) mbits[b] = m;
}

// ---------------- GEMM: C[M,N] = A[M,K](bf16) @ Bt[N,K]^T(bf16) ----------------
// BK=64, K-swizzled LDS (flash7 pattern): LDS row = 64 u16 (128B, 8 slots of 16B);
// LDS (row, slot) holds global slot (slot ^ (row&7)) -> conflict-optimal ds_read_b128.
// EPI 0: write f32 C row-major. EPI 1 (QKV): fused epilogue —
//   q/k: RoPE applied in f32 (pairs acc[nf], acc[nf+2] = dims d, d+32), q scaled 0.125*log2e.
//   v: pkbf-packed 8B stores directly into tiled slot-swizzled vTs [bh][kt][64 d][32 k].
template <int EPI>
__global__ __launch_bounds__(256) void k_gemm(const u16* __restrict__ A, const u16* __restrict__ Bt,
                                              float* __restrict__ Cf, u16* __restrict__ qb,
                                              u16* __restrict__ kb, u16* __restrict__ vTs,
                                              const float* __restrict__ tab, int K) {
  __shared__ u16 lA[128 * 64];
  __shared__ u16 lB[128 * 64];
  int tid = threadIdx.x, w = tid >> 6, l = tid & 63;
  int wm = w >> 1, wn = w & 1;
  int tm = blockIdx.x, tn = blockIdx.y;
  int li = l & 15, lg = l >> 4;
  const u16* gA = A + (size_t)tm * 128 * K;
  const u16* gB = Bt + (size_t)tn * 128 * K;
  f32x4 acc[4][4];
#pragma unroll
  for (int i = 0; i < 4; i++)
#pragma unroll
    for (int j = 0; j < 4; j++) acc[i][j] = (f32x4){0.f, 0.f, 0.f, 0.f};

  // staging geometry: per instr, wave covers chunk = i*4+w (8 rows x 128B = 1KB);
  // lane l -> row-in-chunk lr = l>>3, slot = l&7; source slot = slot ^ (row&7) (row&7 == lr).
  int lr = l >> 3, lslot = l & 7;
  int scol = ((lslot ^ lr) * 8);

  for (int kt = 0; kt < K; kt += 64) {
    __syncthreads();
#pragma unroll
    for (int i = 0; i < 4; ++i) {
      int ch = i * 4 + w;
      int row = ch * 8 + lr;
      gload_lds16(gA + (size_t)row * K + kt + scol, &lA[ch * 512]);
      gload_lds16(gB + (size_t)row * K + kt + scol, &lB[ch * 512]);
    }
    __syncthreads();
#pragma unroll
    for (int kk = 0; kk < 2; ++kk) {
      short8 af[4], bfr[4];
#pragma unroll
      for (int mf = 0; mf < 4; ++mf) {
        int row = wm * 64 + mf * 16 + li;
        af[mf] = *(const short8*)&lA[row * 64 + (((kk * 4 + lg)) ^ (row & 7)) * 8];
      }
#pragma unroll
      for (int nf = 0; nf < 4; ++nf) {
        int row = wn * 64 + nf * 16 + li;
        bfr[nf] = *(const short8*)&lB[row * 64 + (((kk * 4 + lg)) ^ (row & 7)) * 8];
      }
#pragma unroll
      for (int mf = 0; mf < 4; ++mf)
#pragma unroll
        for (int nf = 0; nf < 4; ++nf)
          acc[mf][nf] = __builtin_amdgcn_mfma_f32_16x16x32_bf16(af[mf], bfr[nf], acc[mf][nf], 0, 0, 0);
    }
  }
  if (EPI == 0) {
#pragma unroll
    for (int mf = 0; mf < 4; ++mf) {
      int mg0 = tm * 128 + wm * 64 + mf * 16 + lg * 4;
#pragma unroll
      for (int nf = 0; nf < 4; ++nf) {
        int ng = tn * 128 + wn * 64 + nf * 16 + li;
#pragma unroll
        for (int r = 0; r < 4; ++r)
          Cf[(size_t)(mg0 + r) * 1024 + ng] = acc[mf][nf][r];
      }
    }
  } else {
    int which = tn >> 3;                 // 0=q 1=k 2=v (128-col tiles, 8 per matrix)
    int h = (tn & 7) * 2 + wn;           // head
    int b = tm >> 4;                     // 128 | 2048: block never straddles batches
    if (which < 2) {
      float scale = (which == 0) ? 0.125f * 1.44269504088896f : 1.0f;
      u16* qk = (which == 0 ? qb : kb) + (((size_t)b * HQ + h) * SQ << 6);
#pragma unroll
      for (int mf = 0; mf < 4; ++mf) {
#pragma unroll
        for (int r = 0; r < 4; ++r) {
          int s = (tm * 128 + wm * 64 + mf * 16 + lg * 4 + r) & 2047;
          u16* dst = qk + ((size_t)s << 6);
#pragma unroll
          for (int nf2 = 0; nf2 < 2; ++nf2) {
            int dp = nf2 * 16 + li;      // 0..31
            float2 cs = *(const float2*)&tab[(s * 32 + dp) * 2];
            float a = acc[mf][nf2][r];
            float bb = acc[mf][nf2 + 2][r];
            dst[dp] = f2bf((a * cs.x - bb * cs.y) * scale);
            dst[dp + 32] = f2bf((bb * cs.x + a * cs.y) * scale);
          }
        }
      }
    } else {
      // V: pack 4 consecutive kk (same 16B slot) -> one 8B store
#pragma unroll
      for (int mf = 0; mf < 4; ++mf) {
        int s0 = (tm * 128 + wm * 64 + mf * 16 + lg * 4) & 2047;
        int kt = s0 >> 5, kk0 = s0 & 31;
        int slot = kk0 >> 3;             // constant over r
        size_t tb = (((size_t)(b * HQ + h) * 64 + kt) * 64);
#pragma unroll
        for (int nf = 0; nf < 4; ++nf) {
          int d = nf * 16 + li;
          u32 w0 = pkbf(acc[mf][nf][0], acc[mf][nf][1]);
          u32 w1 = pkbf(acc[mf][nf][2], acc[mf][nf][3]);
          size_t off = (tb + d) * 32 + ((slot ^ ((d >> 1) & 3)) << 3) + (kk0 & 7);
          *(u32x2*)&vTs[off] = (u32x2){w0, w1};
        }
      }
    }
  }
}

// ---------------- flash attention v7 (93us verified): LDS-shared K/V, swapped QK^T ----------------
// Block = 4 waves on q-tiles {qsup*4 .. qsup*4+3} of ONE bh. Per k-tile the block stages
// K (4KB, source-swizzled) + V^T (4KB, pre-swizzled tiled layout) via global_load_lds,
// double-buffered, one barrier per tile. CU-balanced qsup quad {v,7-v,8+v,15-v} (sum 30).
// Waves skip compute entirely for kt > myqt (wave-uniform; barrier stays outside).
__global__ __launch_bounds__(256) void k_flash7(const u16* __restrict__ Q, const u16* __restrict__ Kb,
                                                const u16* __restrict__ VTs, const int* __restrict__ mask,
                                                const u64* __restrict__ mbits, u16* __restrict__ O) {
  __shared__ alignas(16) u16 Kl[2][2048];
  __shared__ alignas(16) u16 Vl[2][2048];
  int bid = blockIdx.x;
  int bh = bid & 63;
  int u = bid >> 6, v = u & 3, k4 = u >> 2;
  int qsup = (k4 == 0) ? v : (k4 == 1) ? 7 - v : (k4 == 2) ? 8 + v : 15 - v;
  int tid = threadIdx.x, w = tid >> 6, l = tid & 63;
  int j = l & 31, hi = l >> 5;
  int myqt = qsup * 4 + w;
  int nt = qsup * 4 + 4;
  int b = bh >> 4, h = bh & 15;
  const int* mp = mask + b * SQ + 4 * hi;
  u64 mb = mbits[b];

  // staging source addresses (per-thread)
  int sr = tid >> 3, sc16 = tid & 7;
  const u16* Kg0 = Kb + ((size_t)bh * SQ) * 64 + sr * 64 + ((sc16 ^ (sr & 7)) * 8);  // + kt*2048
  const u16* Vg0 = VTs + ((size_t)bh * 64) * 2048 + tid * 8;                          // + kt*2048
  u16* KlB = &Kl[0][(size_t)w * 512];  // wave-uniform dest bases (buffer toggled by +2048 u16)
  u16* VlB = &Vl[0][(size_t)w * 512];

  // Q fragments (B operand)
  int qbase = myqt * 32;
  const u16* qp = Q + ((size_t)bh * SQ + qbase + j) * 64 + hi * 8;
  short8 qf[4];
#pragma unroll
  for (int kb = 0; kb < 4; ++kb) qf[kb] = *(const short8*)(qp + kb * 16);

  f32x16 o0, o1;
#pragma unroll
  for (int i = 0; i < 16; ++i) { o0[i] = 0.f; o1[i] = 0.f; }
  float mrun = -INFINITY, lrun = 0.f;

  int swK = (j & 7), swV = (j >> 1) & 3;

  // prologue: stage tile 0 into buffer 0
  gload_lds16(Kg0, KlB);
  gload_lds16(Vg0, VlB);
  __syncthreads();

  for (int kt = 0; kt < nt; ++kt) {
    int cur = kt & 1;
    if (kt + 1 < nt) {  // stage next tile into other buffer
      gload_lds16(Kg0 + (size_t)(kt + 1) * 2048, KlB + (cur ^ 1) * 2048);
      gload_lds16(Vg0 + (size_t)(kt + 1) * 2048, VlB + (cur ^ 1) * 2048);
    }

    if (kt <= myqt) {
      const u16* Kc = Kl[cur];
      const u16* Vc = Vl[cur];

      short8 kcf[4];
#pragma unroll
      for (int kb = 0; kb < 4; ++kb)
        kcf[kb] = *(const short8*)&Kc[j * 64 + (((hi + 2 * kb)) ^ swK) * 8];

      f32x16 s;
#pragma unroll
      for (int i = 0; i < 16; ++i) s[i] = 0.f;
      __builtin_amdgcn_s_setprio(1);
#pragma unroll
      for (int kb = 0; kb < 4; ++kb)
        s = __builtin_amdgcn_mfma_f32_32x32x16_bf16(kcf[kb], qf[kb], s, 0, 0, 0);
      __builtin_amdgcn_s_setprio(0);

      // V fragments for this tile (LDS; scheduled early by compiler)
      short8 va0 = *(const short8*)&Vc[j * 32 + ((hi) ^ swV) * 8];
      short8 va1 = *(const short8*)&Vc[j * 32 + ((hi + 2) ^ swV) * 8];
      short8 vb0 = *(const short8*)&Vc[(j + 32) * 32 + ((hi) ^ swV) * 8];
      short8 vb1 = *(const short8*)&Vc[(j + 32) * 32 + ((hi + 2) ^ swV) * 8];

      // pad mask: only when this 32-chunk has zeros (never in this harness)
      if (!((mb >> kt) & 1ull)) {
#pragma unroll
        for (int rq = 0; rq < 4; ++rq) {
          int4 mv = *(const int4*)(mp + kt * 32 + 8 * rq);
          if (!mv.x) s[4 * rq + 0] = -INFINITY;
          if (!mv.y) s[4 * rq + 1] = -INFINITY;
          if (!mv.z) s[4 * rq + 2] = -INFINITY;
          if (!mv.w) s[4 * rq + 3] = -INFINITY;
        }
      }
      // causal: diagonal tile masks k>q
      if (kt == myqt) {
#pragma unroll
        for (int rq = 0; rq < 4; ++rq)
#pragma unroll
          for (int t = 0; t < 4; ++t)
            if (8 * rq + 4 * hi + t > j) s[4 * rq + t] = -INFINITY;
      }

      // online softmax in log2 domain, fully in-register
      float t0 = fmaxf(fmaxf(fmaxf(s[0], s[1]), fmaxf(s[2], s[3])),
                       fmaxf(fmaxf(s[4], s[5]), fmaxf(s[6], s[7])));
      t0 = fmaxf(t0, fmaxf(fmaxf(fmaxf(s[8], s[9]), fmaxf(s[10], s[11])),
                           fmaxf(fmaxf(s[12], s[13]), fmaxf(s[14], s[15]))));
      if (!__all(t0 <= mrun + 8.0f)) {  // defer-max (T13)
        float tm2 = xmax32(t0);
        float mn = fmaxf(fmaxf(mrun, tm2), -1e30f);
        float alpha = fexp2(mrun - mn);
        mrun = mn;
        lrun *= alpha;
#pragma unroll
        for (int i = 0; i < 16; ++i) { o0[i] *= alpha; o1[i] *= alpha; }
      }
      float ts = 0.f;
#pragma unroll
      for (int i = 0; i < 16; ++i) {
        float pv = fexp2(s[i] - mrun);
        s[i] = pv;
        ts += pv;
      }
      lrun += ts;

      // pack P^T into B fragments: cvt_pk pairs + one cross-half shfl per word-pair
      u32 pa[4], pb[4];
#pragma unroll
      for (int q2 = 0; q2 < 4; ++q2) {
        pa[q2] = pkbf(s[4 * q2 + 0], s[4 * q2 + 1]);
        pb[q2] = pkbf(s[4 * q2 + 2], s[4 * q2 + 3]);
      }
      u32 ya01 = xword(hi ? pa[0] : pa[1]);
      u32 yb01 = xword(hi ? pb[0] : pb[1]);
      u32 ya23 = xword(hi ? pa[2] : pa[3]);
      u32 yb23 = xword(hi ? pb[2] : pb[3]);
      union { short8 s8; u32 wd[4]; } f0, f1;
      f0.wd[0] = hi ? ya01 : pa[0];
      f0.wd[1] = hi ? yb01 : pb[0];
      f0.wd[2] = hi ? pa[1] : ya01;
      f0.wd[3] = hi ? pb[1] : yb01;
      f1.wd[0] = hi ? ya23 : pa[2];
      f1.wd[1] = hi ? yb23 : pb[2];
      f1.wd[2] = hi ? pa[3] : ya23;
      f1.wd[3] = hi ? pb[3] : yb23;

      // PV: O^T += V^T(frag A) x P^T(frag B)
      __builtin_amdgcn_s_setprio(1);
      o0 = __builtin_amdgcn_mfma_f32_32x32x16_bf16(va0, f0.s8, o0, 0, 0, 0);
      o0 = __builtin_amdgcn_mfma_f32_32x32x16_bf16(va1, f1.s8, o0, 0, 0, 0);
      o1 = __builtin_amdgcn_mfma_f32_32x32x16_bf16(vb0, f0.s8, o1, 0, 0, 0);
      o1 = __builtin_amdgcn_mfma_f32_32x32x16_bf16(vb1, f1.s8, o1, 0, 0, 0);
      __builtin_amdgcn_s_setprio(0);
    }

    __syncthreads();  // drains vmem (next stage) + all waves done reading cur
  }

  // epilogue: merge the two halves' lrun, store q rows
  float lfull = xsum32(lrun);
  float inv = 1.0f / lfull;
  u16* ob = O + ((size_t)b * SQ + qbase + j) * DQ + h * 64 + 4 * hi;
#pragma unroll
  for (int q2 = 0; q2 < 4; ++q2) {
#pragma unroll
    for (int e = 0; e < 2; ++e) {
      *(u32*)(ob + 8 * q2 + 2 * e) = pkbf(o0[4 * q2 + 2 * e] * inv, o0[4 * q2 + 2 * e + 1] * inv);
      *(u32*)(ob + 32 + 8 * q2 + 2 * e) = pkbf(o1[4 * q2 + 2 * e] * inv, o1[4 * q2 + 2 * e + 1] * inv);
    }
  }
}

extern "C" void kernel_launch(void* const* d_in, const int* in_sizes, int n_in,
                              void* d_out, int out_size, void* d_ws, size_t ws_size,
                              hipStream_t stream) {
  const float* x = (const float*)d_in[0];
  const int* mask = (const int*)d_in[1];
  const float* wqkv = (const float*)d_in[2];
  const float* wout = (const float*)d_in[3];
  float* out = (float*)d_out;
  char* ws = (char*)d_ws;

  u16* xb    = (u16*)(ws + 0);           // 16 MB
  u16* wqkvT = (u16*)(ws + 16777216);    // 6 MB  [3072][1024]
  u16* woutT = (u16*)(ws + 23068672);    // 2 MB  [1024][1024]
  u16* qbuf  = (u16*)(ws + 25165824);    // 16 MB [bh][S][64]
  u16* kbuf  = (u16*)(ws + 41943040);    // 16 MB
  u16* vTs   = (u16*)(ws + 75497472);    // 16 MB [bh][64 kt][64][32] slot-swizzled
  u16* attnb = (u16*)(ws + 92274688);    // 16 MB [B*S][1024]
  float* tab = (float*)(ws + 109051904); // 512 KB
  u64* mbits = (u64*)(ws + 109576192);   // 32 B

  k_rope_table<<<256, 256, 0, stream>>>(tab);
  k_mflags<<<1, 256, 0, stream>>>(mask, mbits);
  k_cvt<<<8192, 256, 0, stream>>>(x, xb, 2097152);
  k_transpose_cvt<<<dim3(96, 32), 256, 0, stream>>>(wqkv, wqkvT, 1024, 3072);
  k_transpose_cvt<<<dim3(32, 32), 256, 0, stream>>>(wout, woutT, 1024, 1024);
  k_gemm<1><<<dim3(64, 24), 256, 0, stream>>>(xb, wqkvT, nullptr, qbuf, kbuf, vTs, tab, 1024);
  k_flash7<<<1024, 256, 0, stream>>>(qbuf, kbuf, vTs, mask, mbits, attnb);
  k_gemm<0><<<dim3(64, 8), 256, 0, stream>>>(attnb, woutT, out, nullptr, nullptr, nullptr, nullptr, 1024);
}

// Round 15
// 187.993 us; speedup vs baseline: 1.3627x; 1.0544x over previous
//
#include <hip/hip_runtime.h>

#define BQ 4
#define SQ 2048
#define DQ 1024
#define HQ 16
#define BHQ 64

typedef __attribute__((ext_vector_type(8))) short short8;
typedef __attribute__((ext_vector_type(4))) float f32x4;
typedef __attribute__((ext_vector_type(16))) float f32x16;
typedef __attribute__((ext_vector_type(2))) unsigned int u32x2;
typedef unsigned short u16;
typedef unsigned int u32;
typedef unsigned long long u64;

__device__ __forceinline__ u16 f2bf(float f) {
  u32 u = __float_as_uint(f);
  u32 r = u + 0x7fffu + ((u >> 16) & 1u);
  return (u16)(r >> 16);
}
__device__ __forceinline__ float bf2f(u16 h) {
  return __uint_as_float(((u32)h) << 16);
}

// packed f32x2 -> bf16x2 (RNE), one instruction
__device__ __forceinline__ u32 pkbf(float lo, float hi_) {
  u32 r;
  asm("v_cvt_pk_bf16_f32 %0, %1, %2" : "=v"(r) : "v"(lo), "v"(hi_));
  return r;
}
// raw v_exp_f32: computes 2^x (input already in log2 domain)
__device__ __forceinline__ float fexp2(float x) {
  float r;
  asm("v_exp_f32 %0, %1" : "=v"(r) : "v"(x));
  return r;
}
// cross-half exchange via shfl (known-correct)
__device__ __forceinline__ float xmax32(float x) { return fmaxf(x, __shfl_xor(x, 32)); }
__device__ __forceinline__ float xsum32(float x) { return x + __shfl_xor(x, 32); }
__device__ __forceinline__ u32 xword(u32 send) { return (u32)__shfl_xor((int)send, 32); }

// async global->LDS, 16B per lane. LDS dest must be wave-uniform; HW adds lane*16.
__device__ __forceinline__ void gload_lds16(const void* g, void* l) {
  __builtin_amdgcn_global_load_lds(
      (const __attribute__((address_space(1))) u32*)(unsigned long long)g,
      (__attribute__((address_space(3))) u32*)(u32)(unsigned long long)l,
      16, 0, 0);
}

// ---------------- fused prep: cvt x | transpose wqkv | transpose wout | rope tab | mflags ----------------
__device__ __forceinline__ void transpose_body(const float* __restrict__ in, u16* __restrict__ out,
                                               int R, int C, int bx, int by, int tid) {
  __shared__ float t[32][33];
  int c0 = bx * 32, r0 = by * 32;
  int tx = tid & 31, ty = tid >> 5;
  for (int rr = ty; rr < 32; rr += 8)
    t[rr][tx] = in[(size_t)(r0 + rr) * C + c0 + tx];
  __syncthreads();
  for (int rr = ty; rr < 32; rr += 8)
    out[(size_t)(c0 + rr) * R + r0 + tx] = f2bf(t[tx][rr]);
}

__global__ __launch_bounds__(256) void k_prep(const float* __restrict__ x, u16* __restrict__ xb,
                                              const float* __restrict__ wqkv, u16* __restrict__ wqkvT,
                                              const float* __restrict__ wout, u16* __restrict__ woutT,
                                              float* __restrict__ tab, const int* __restrict__ mask,
                                              u64* __restrict__ mbits) {
  int bid = blockIdx.x, tid = threadIdx.x;
  if (bid < 8192) {                       // cvt x -> bf16 (2M float4)
    int i = bid * 256 + tid;
    float4 v = ((const float4*)x)[i];
    ushort4 o;
    o.x = f2bf(v.x); o.y = f2bf(v.y); o.z = f2bf(v.z); o.w = f2bf(v.w);
    ((ushort4*)xb)[i] = o;
  } else if (bid < 11264) {               // transpose wqkv [1024][3072] -> [3072][1024]
    int t = bid - 8192;
    transpose_body(wqkv, wqkvT, 1024, 3072, t % 96, t / 96, tid);
  } else if (bid < 12288) {               // transpose wout [1024][1024]
    int t = bid - 11264;
    transpose_body(wout, woutT, 1024, 1024, t % 32, t / 32, tid);
  } else if (bid < 12544) {               // rope cos/sin table [S][32][2]
    int i = (bid - 12288) * 256 + tid;
    int s = i >> 5, dp = i & 31;
    float invf = expf(-0.28782313662425576f * (float)dp);
    float ang = (float)s * invf;
    tab[i * 2] = cosf(ang);
    tab[i * 2 + 1] = sinf(ang);
  } else {                                // mask bitmask (1 block: wave=batch, lane=chunk)
    int b = tid >> 6, c = tid & 63;
    int all1 = 1;
    for (int i = 0; i < 32; ++i) all1 &= (mask[b * SQ + c * 32 + i] != 0) ? 1 : 0;
    u64 m = __ballot(all1);
    if (c == 0) mbits[b] = m;
  }
}

// ---------------- GEMM: C[M,N] = A[M,K](bf16) @ Bt[N,K]^T(bf16) ----------------
// BK=64, K-swizzled LDS (flash7 pattern). 1D grid with XCD-chunked (tm,tn) map:
// xcd=bid&7 owns tm in [xcd*8, xcd*8+8) (2MB of A = L2-resident) across all tn epochs.
// EPI 0: write f32 C row-major. EPI 1 (QKV): fused RoPE q/k + packed V scatter to vTs.
template <int EPI>
__global__ __launch_bounds__(256) void k_gemm(const u16* __restrict__ A, const u16* __restrict__ Bt,
                                              float* __restrict__ Cf, u16* __restrict__ qb,
                                              u16* __restrict__ kb, u16* __restrict__ vTs,
                                              const float* __restrict__ tab, int K) {
  __shared__ u16 lA[128 * 64];
  __shared__ u16 lB[128 * 64];
  int bid = blockIdx.x;
  int i_ = bid >> 3;
  int tm = (bid & 7) * 8 + (i_ & 7);
  int tn = i_ >> 3;
  int tid = threadIdx.x, w = tid >> 6, l = tid & 63;
  int wm = w >> 1, wn = w & 1;
  int li = l & 15, lg = l >> 4;
  const u16* gA = A + (size_t)tm * 128 * K;
  const u16* gB = Bt + (size_t)tn * 128 * K;
  f32x4 acc[4][4];
#pragma unroll
  for (int i = 0; i < 4; i++)
#pragma unroll
    for (int j = 0; j < 4; j++) acc[i][j] = (f32x4){0.f, 0.f, 0.f, 0.f};

  int lr = l >> 3, lslot = l & 7;
  int scol = ((lslot ^ lr) * 8);

  for (int kt = 0; kt < K; kt += 64) {
    __syncthreads();
#pragma unroll
    for (int i = 0; i < 4; ++i) {
      int ch = i * 4 + w;
      int row = ch * 8 + lr;
      gload_lds16(gA + (size_t)row * K + kt + scol, &lA[ch * 512]);
      gload_lds16(gB + (size_t)row * K + kt + scol, &lB[ch * 512]);
    }
    __syncthreads();
#pragma unroll
    for (int kk = 0; kk < 2; ++kk) {
      short8 af[4], bfr[4];
#pragma unroll
      for (int mf = 0; mf < 4; ++mf) {
        int row = wm * 64 + mf * 16 + li;
        af[mf] = *(const short8*)&lA[row * 64 + (((kk * 4 + lg)) ^ (row & 7)) * 8];
      }
#pragma unroll
      for (int nf = 0; nf < 4; ++nf) {
        int row = wn * 64 + nf * 16 + li;
        bfr[nf] = *(const short8*)&lB[row * 64 + (((kk * 4 + lg)) ^ (row & 7)) * 8];
      }
#pragma unroll
      for (int mf = 0; mf < 4; ++mf)
#pragma unroll
        for (int nf = 0; nf < 4; ++nf)
          acc[mf][nf] = __builtin_amdgcn_mfma_f32_16x16x32_bf16(af[mf], bfr[nf], acc[mf][nf], 0, 0, 0);
    }
  }
  if (EPI == 0) {
#pragma unroll
    for (int mf = 0; mf < 4; ++mf) {
      int mg0 = tm * 128 + wm * 64 + mf * 16 + lg * 4;
#pragma unroll
      for (int nf = 0; nf < 4; ++nf) {
        int ng = tn * 128 + wn * 64 + nf * 16 + li;
#pragma unroll
        for (int r = 0; r < 4; ++r)
          Cf[(size_t)(mg0 + r) * 1024 + ng] = acc[mf][nf][r];
      }
    }
  } else {
    int which = tn >> 3;                 // 0=q 1=k 2=v (128-col tiles, 8 per matrix)
    int h = (tn & 7) * 2 + wn;           // head
    int b = tm >> 4;                     // 128 | 2048: block never straddles batches
    if (which < 2) {
      float scale = (which == 0) ? 0.125f * 1.44269504088896f : 1.0f;
      u16* qk = (which == 0 ? qb : kb) + (((size_t)b * HQ + h) * SQ << 6);
#pragma unroll
      for (int mf = 0; mf < 4; ++mf) {
#pragma unroll
        for (int r = 0; r < 4; ++r) {
          int s = (tm * 128 + wm * 64 + mf * 16 + lg * 4 + r) & 2047;
          u16* dst = qk + ((size_t)s << 6);
#pragma unroll
          for (int nf2 = 0; nf2 < 2; ++nf2) {
            int dp = nf2 * 16 + li;      // 0..31
            float2 cs = *(const float2*)&tab[(s * 32 + dp) * 2];
            float a = acc[mf][nf2][r];
            float bb = acc[mf][nf2 + 2][r];
            dst[dp] = f2bf((a * cs.x - bb * cs.y) * scale);
            dst[dp + 32] = f2bf((bb * cs.x + a * cs.y) * scale);
          }
        }
      }
    } else {
      // V: pack 4 consecutive kk (same 16B slot) -> one 8B store
#pragma unroll
      for (int mf = 0; mf < 4; ++mf) {
        int s0 = (tm * 128 + wm * 64 + mf * 16 + lg * 4) & 2047;
        int kt = s0 >> 5, kk0 = s0 & 31;
        int slot = kk0 >> 3;             // constant over r
        size_t tb = (((size_t)(b * HQ + h) * 64 + kt) * 64);
#pragma unroll
        for (int nf = 0; nf < 4; ++nf) {
          int d = nf * 16 + li;
          u32 w0 = pkbf(acc[mf][nf][0], acc[mf][nf][1]);
          u32 w1 = pkbf(acc[mf][nf][2], acc[mf][nf][3]);
          size_t off = (tb + d) * 32 + ((slot ^ ((d >> 1) & 3)) << 3) + (kk0 & 7);
          *(u32x2*)&vTs[off] = (u32x2){w0, w1};
        }
      }
    }
  }
}

// ---------------- flash attention v7 (83us verified): LDS-shared K/V, swapped QK^T ----------------
// Block = 4 waves on q-tiles {qsup*4 .. qsup*4+3} of ONE bh. Per k-tile the block stages
// K (4KB, source-swizzled) + V^T (4KB, pre-swizzled tiled layout) via global_load_lds,
// double-buffered, one barrier per tile. CU-balanced qsup quad {v,7-v,8+v,15-v} (sum 30).
// Waves skip compute entirely for kt > myqt (wave-uniform; barrier stays outside).
__global__ __launch_bounds__(256) void k_flash7(const u16* __restrict__ Q, const u16* __restrict__ Kb,
                                                const u16* __restrict__ VTs, const int* __restrict__ mask,
                                                const u64* __restrict__ mbits, u16* __restrict__ O) {
  __shared__ alignas(16) u16 Kl[2][2048];
  __shared__ alignas(16) u16 Vl[2][2048];
  int bid = blockIdx.x;
  int bh = bid & 63;
  int u = bid >> 6, v = u & 3, k4 = u >> 2;
  int qsup = (k4 == 0) ? v : (k4 == 1) ? 7 - v : (k4 == 2) ? 8 + v : 15 - v;
  int tid = threadIdx.x, w = tid >> 6, l = tid & 63;
  int j = l & 31, hi = l >> 5;
  int myqt = qsup * 4 + w;
  int nt = qsup * 4 + 4;
  int b = bh >> 4, h = bh & 15;
  const int* mp = mask + b * SQ + 4 * hi;
  u64 mb = mbits[b];

  // staging source addresses (per-thread)
  int sr = tid >> 3, sc16 = tid & 7;
  const u16* Kg0 = Kb + ((size_t)bh * SQ) * 64 + sr * 64 + ((sc16 ^ (sr & 7)) * 8);  // + kt*2048
  const u16* Vg0 = VTs + ((size_t)bh * 64) * 2048 + tid * 8;                          // + kt*2048
  u16* KlB = &Kl[0][(size_t)w * 512];  // wave-uniform dest bases (buffer toggled by +2048 u16)
  u16* VlB = &Vl[0][(size_t)w * 512];

  // Q fragments (B operand)
  int qbase = myqt * 32;
  const u16* qp = Q + ((size_t)bh * SQ + qbase + j) * 64 + hi * 8;
  short8 qf[4];
#pragma unroll
  for (int kb = 0; kb < 4; ++kb) qf[kb] = *(const short8*)(qp + kb * 16);

  f32x16 o0, o1;
#pragma unroll
  for (int i = 0; i < 16; ++i) { o0[i] = 0.f; o1[i] = 0.f; }
  float mrun = -INFINITY, lrun = 0.f;

  int swK = (j & 7), swV = (j >> 1) & 3;

  // prologue: stage tile 0 into buffer 0
  gload_lds16(Kg0, KlB);
  gload_lds16(Vg0, VlB);
  __syncthreads();

  for (int kt = 0; kt < nt; ++kt) {
    int cur = kt & 1;
    if (kt + 1 < nt) {  // stage next tile into other buffer
      gload_lds16(Kg0 + (size_t)(kt + 1) * 2048, KlB + (cur ^ 1) * 2048);
      gload_lds16(Vg0 + (size_t)(kt + 1) * 2048, VlB + (cur ^ 1) * 2048);
    }

    if (kt <= myqt) {
      const u16* Kc = Kl[cur];
      const u16* Vc = Vl[cur];

      short8 kcf[4];
#pragma unroll
      for (int kb = 0; kb < 4; ++kb)
        kcf[kb] = *(const short8*)&Kc[j * 64 + (((hi + 2 * kb)) ^ swK) * 8];

      f32x16 s;
#pragma unroll
      for (int i = 0; i < 16; ++i) s[i] = 0.f;
      __builtin_amdgcn_s_setprio(1);
#pragma unroll
      for (int kb = 0; kb < 4; ++kb)
        s = __builtin_amdgcn_mfma_f32_32x32x16_bf16(kcf[kb], qf[kb], s, 0, 0, 0);
      __builtin_amdgcn_s_setprio(0);

      // V fragments for this tile (LDS; scheduled early by compiler)
      short8 va0 = *(const short8*)&Vc[j * 32 + ((hi) ^ swV) * 8];
      short8 va1 = *(const short8*)&Vc[j * 32 + ((hi + 2) ^ swV) * 8];
      short8 vb0 = *(const short8*)&Vc[(j + 32) * 32 + ((hi) ^ swV) * 8];
      short8 vb1 = *(const short8*)&Vc[(j + 32) * 32 + ((hi + 2) ^ swV) * 8];

      // pad mask: only when this 32-chunk has zeros (never in this harness)
      if (!((mb >> kt) & 1ull)) {
#pragma unroll
        for (int rq = 0; rq < 4; ++rq) {
          int4 mv = *(const int4*)(mp + kt * 32 + 8 * rq);
          if (!mv.x) s[4 * rq + 0] = -INFINITY;
          if (!mv.y) s[4 * rq + 1] = -INFINITY;
          if (!mv.z) s[4 * rq + 2] = -INFINITY;
          if (!mv.w) s[4 * rq + 3] = -INFINITY;
        }
      }
      // causal: diagonal tile masks k>q
      if (kt == myqt) {
#pragma unroll
        for (int rq = 0; rq < 4; ++rq)
#pragma unroll
          for (int t = 0; t < 4; ++t)
            if (8 * rq + 4 * hi + t > j) s[4 * rq + t] = -INFINITY;
      }

      // online softmax in log2 domain, fully in-register
      float t0 = fmaxf(fmaxf(fmaxf(s[0], s[1]), fmaxf(s[2], s[3])),
                       fmaxf(fmaxf(s[4], s[5]), fmaxf(s[6], s[7])));
      t0 = fmaxf(t0, fmaxf(fmaxf(fmaxf(s[8], s[9]), fmaxf(s[10], s[11])),
                           fmaxf(fmaxf(s[12], s[13]), fmaxf(s[14], s[15]))));
      if (!__all(t0 <= mrun + 8.0f)) {  // defer-max (T13)
        float tm2 = xmax32(t0);
        float mn = fmaxf(fmaxf(mrun, tm2), -1e30f);
        float alpha = fexp2(mrun - mn);
        mrun = mn;
        lrun *= alpha;
#pragma unroll
        for (int i = 0; i < 16; ++i) { o0[i] *= alpha; o1[i] *= alpha; }
      }
      float ts = 0.f;
#pragma unroll
      for (int i = 0; i < 16; ++i) {
        float pv = fexp2(s[i] - mrun);
        s[i] = pv;
        ts += pv;
      }
      lrun += ts;

      // pack P^T into B fragments: cvt_pk pairs + one cross-half shfl per word-pair
      u32 pa[4], pb[4];
#pragma unroll
      for (int q2 = 0; q2 < 4; ++q2) {
        pa[q2] = pkbf(s[4 * q2 + 0], s[4 * q2 + 1]);
        pb[q2] = pkbf(s[4 * q2 + 2], s[4 * q2 + 3]);
      }
      u32 ya01 = xword(hi ? pa[0] : pa[1]);
      u32 yb01 = xword(hi ? pb[0] : pb[1]);
      u32 ya23 = xword(hi ? pa[2] : pa[3]);
      u32 yb23 = xword(hi ? pb[2] : pb[3]);
      union { short8 s8; u32 wd[4]; } f0, f1;
      f0.wd[0] = hi ? ya01 : pa[0];
      f0.wd[1] = hi ? yb01 : pb[0];
      f0.wd[2] = hi ? pa[1] : ya01;
      f0.wd[3] = hi ? pb[1] : yb01;
      f1.wd[0] = hi ? ya23 : pa[2];
      f1.wd[1] = hi ? yb23 : pb[2];
      f1.wd[2] = hi ? pa[3] : ya23;
      f1.wd[3] = hi ? pb[3] : yb23;

      // PV: O^T += V^T(frag A) x P^T(frag B)
      __builtin_amdgcn_s_setprio(1);
      o0 = __builtin_amdgcn_mfma_f32_32x32x16_bf16(va0, f0.s8, o0, 0, 0, 0);
      o0 = __builtin_amdgcn_mfma_f32_32x32x16_bf16(va1, f1.s8, o0, 0, 0, 0);
      o1 = __builtin_amdgcn_mfma_f32_32x32x16_bf16(vb0, f0.s8, o1, 0, 0, 0);
      o1 = __builtin_amdgcn_mfma_f32_32x32x16_bf16(vb1, f1.s8, o1, 0, 0, 0);
      __builtin_amdgcn_s_setprio(0);
    }

    __syncthreads();  // drains vmem (next stage) + all waves done reading cur
  }

  // epilogue: merge the two halves' lrun, store q rows
  float lfull = xsum32(lrun);
  float inv = 1.0f / lfull;
  u16* ob = O + ((size_t)b * SQ + qbase + j) * DQ + h * 64 + 4 * hi;
#pragma unroll
  for (int q2 = 0; q2 < 4; ++q2) {
#pragma unroll
    for (int e = 0; e < 2; ++e) {
      *(u32*)(ob + 8 * q2 + 2 * e) = pkbf(o0[4 * q2 + 2 * e] * inv, o0[4 * q2 + 2 * e + 1] * inv);
      *(u32*)(ob + 32 + 8 * q2 + 2 * e) = pkbf(o1[4 * q2 + 2 * e] * inv, o1[4 * q2 + 2 * e + 1] * inv);
    }
  }
}

extern "C" void kernel_launch(void* const* d_in, const int* in_sizes, int n_in,
                              void* d_out, int out_size, void* d_ws, size_t ws_size,
                              hipStream_t stream) {
  const float* x = (const float*)d_in[0];
  const int* mask = (const int*)d_in[1];
  const float* wqkv = (const float*)d_in[2];
  const float* wout = (const float*)d_in[3];
  float* out = (float*)d_out;
  char* ws = (char*)d_ws;

  u16* xb    = (u16*)(ws + 0);           // 16 MB
  u16* wqkvT = (u16*)(ws + 16777216);    // 6 MB  [3072][1024]
  u16* woutT = (u16*)(ws + 23068672);    // 2 MB  [1024][1024]
  u16* qbuf  = (u16*)(ws + 25165824);    // 16 MB [bh][S][64]
  u16* kbuf  = (u16*)(ws + 41943040);    // 16 MB
  u16* vTs   = (u16*)(ws + 75497472);    // 16 MB [bh][64 kt][64][32] slot-swizzled
  u16* attnb = (u16*)(ws + 92274688);    // 16 MB [B*S][1024]
  float* tab = (float*)(ws + 109051904); // 512 KB
  u64* mbits = (u64*)(ws + 109576192);   // 32 B

  k_prep<<<12545, 256, 0, stream>>>(x, xb, wqkv, wqkvT, wout, woutT, tab, mask, mbits);
  k_gemm<1><<<1536, 256, 0, stream>>>(xb, wqkvT, nullptr, qbuf, kbuf, vTs, tab, 1024);
  k_flash7<<<1024, 256, 0, stream>>>(qbuf, kbuf, vTs, mask, mbits, attnb);
  k_gemm<0><<<512, 256, 0, stream>>>(attnb, woutT, out, nullptr, nullptr, nullptr, nullptr, 1024);
}

// Round 16
// 185.772 us; speedup vs baseline: 1.3790x; 1.0120x over previous
//
#include <hip/hip_runtime.h>

#define BQ 4
#define SQ 2048
#define DQ 1024
#define HQ 16
#define BHQ 64

typedef __attribute__((ext_vector_type(8))) short short8;
typedef __attribute__((ext_vector_type(4))) float f32x4;
typedef __attribute__((ext_vector_type(16))) float f32x16;
typedef __attribute__((ext_vector_type(2))) unsigned int u32x2;
typedef unsigned short u16;
typedef unsigned int u32;
typedef unsigned long long u64;

__device__ __forceinline__ u16 f2bf(float f) {
  u32 u = __float_as_uint(f);
  u32 r = u + 0x7fffu + ((u >> 16) & 1u);
  return (u16)(r >> 16);
}
__device__ __forceinline__ float bf2f(u16 h) {
  return __uint_as_float(((u32)h) << 16);
}

// packed f32x2 -> bf16x2 (RNE), one instruction
__device__ __forceinline__ u32 pkbf(float lo, float hi_) {
  u32 r;
  asm("v_cvt_pk_bf16_f32 %0, %1, %2" : "=v"(r) : "v"(lo), "v"(hi_));
  return r;
}
// raw v_exp_f32: computes 2^x (input already in log2 domain)
__device__ __forceinline__ float fexp2(float x) {
  float r;
  asm("v_exp_f32 %0, %1" : "=v"(r) : "v"(x));
  return r;
}
// cross-half exchange via shfl (known-correct)
__device__ __forceinline__ float xmax32(float x) { return fmaxf(x, __shfl_xor(x, 32)); }
__device__ __forceinline__ float xsum32(float x) { return x + __shfl_xor(x, 32); }
__device__ __forceinline__ u32 xword(u32 send) { return (u32)__shfl_xor((int)send, 32); }

// async global->LDS, 16B per lane. LDS dest must be wave-uniform; HW adds lane*16.
__device__ __forceinline__ void gload_lds16(const void* g, void* l) {
  __builtin_amdgcn_global_load_lds(
      (const __attribute__((address_space(1))) u32*)(unsigned long long)g,
      (__attribute__((address_space(3))) u32*)(u32)(unsigned long long)l,
      16, 0, 0);
}

// ---------------- fused prep: cvt x | transpose wqkv | transpose wout | rope tab | mflags ----------------
__device__ __forceinline__ void transpose_body(const float* __restrict__ in, u16* __restrict__ out,
                                               int R, int C, int bx, int by, int tid) {
  __shared__ float t[32][33];
  int c0 = bx * 32, r0 = by * 32;
  int tx = tid & 31, ty = tid >> 5;
  for (int rr = ty; rr < 32; rr += 8)
    t[rr][tx] = in[(size_t)(r0 + rr) * C + c0 + tx];
  __syncthreads();
  for (int rr = ty; rr < 32; rr += 8)
    out[(size_t)(c0 + rr) * R + r0 + tx] = f2bf(t[tx][rr]);
}

__global__ __launch_bounds__(256) void k_prep(const float* __restrict__ x, u16* __restrict__ xb,
                                              const float* __restrict__ wqkv, u16* __restrict__ wqkvT,
                                              const float* __restrict__ wout, u16* __restrict__ woutT,
                                              float* __restrict__ tab, const int* __restrict__ mask,
                                              u64* __restrict__ mbits) {
  int bid = blockIdx.x, tid = threadIdx.x;
  if (bid < 8192) {                       // cvt x -> bf16 (2M float4)
    int i = bid * 256 + tid;
    float4 v = ((const float4*)x)[i];
    ushort4 o;
    o.x = f2bf(v.x); o.y = f2bf(v.y); o.z = f2bf(v.z); o.w = f2bf(v.w);
    ((ushort4*)xb)[i] = o;
  } else if (bid < 11264) {               // transpose wqkv [1024][3072] -> [3072][1024]
    int t = bid - 8192;
    transpose_body(wqkv, wqkvT, 1024, 3072, t % 96, t / 96, tid);
  } else if (bid < 12288) {               // transpose wout [1024][1024]
    int t = bid - 11264;
    transpose_body(wout, woutT, 1024, 1024, t % 32, t / 32, tid);
  } else if (bid < 12544) {               // rope cos/sin table [S][32][2]
    int i = (bid - 12288) * 256 + tid;
    int s = i >> 5, dp = i & 31;
    float invf = expf(-0.28782313662425576f * (float)dp);
    float ang = (float)s * invf;
    tab[i * 2] = cosf(ang);
    tab[i * 2 + 1] = sinf(ang);
  } else {                                // mask bitmask (1 block: wave=batch, lane=chunk)
    int b = tid >> 6, c = tid & 63;
    int all1 = 1;
    for (int i = 0; i < 32; ++i) all1 &= (mask[b * SQ + c * 32 + i] != 0) ? 1 : 0;
    u64 m = __ballot(all1);
    if (c == 0) mbits[b] = m;
  }
}

// ---------------- GEMM: C[M,N] = A[M,K](bf16) @ Bt[N,K]^T(bf16) ----------------
// BK=64, K-swizzled LDS. 1D grid with XCD-chunked (tm,tn) map: xcd=bid&7 owns
// tm in [xcd*8, xcd*8+8) (2MB of A = L2-resident) across all tn epochs.
// EPI 0: write f32 C row-major. EPI 1 (QKV): fused RoPE q/k + tiled K/V scatter:
//   kbuf tiled [bh][kt][8 slot=d>>3][32 j=s&31][8 e]   (bank-optimal flash reads)
//   vTs  tiled [bh][kt][4 slot=k>>3][64 d][8 e]
template <int EPI>
__global__ __launch_bounds__(256) void k_gemm(const u16* __restrict__ A, const u16* __restrict__ Bt,
                                              float* __restrict__ Cf, u16* __restrict__ qb,
                                              u16* __restrict__ kb, u16* __restrict__ vTs,
                                              const float* __restrict__ tab, int K) {
  __shared__ u16 lA[128 * 64];
  __shared__ u16 lB[128 * 64];
  int bid = blockIdx.x;
  int i_ = bid >> 3;
  int tm = (bid & 7) * 8 + (i_ & 7);
  int tn = i_ >> 3;
  int tid = threadIdx.x, w = tid >> 6, l = tid & 63;
  int wm = w >> 1, wn = w & 1;
  int li = l & 15, lg = l >> 4;
  const u16* gA = A + (size_t)tm * 128 * K;
  const u16* gB = Bt + (size_t)tn * 128 * K;
  f32x4 acc[4][4];
#pragma unroll
  for (int i = 0; i < 4; i++)
#pragma unroll
    for (int j = 0; j < 4; j++) acc[i][j] = (f32x4){0.f, 0.f, 0.f, 0.f};

  int lr = l >> 3, lslot = l & 7;
  int scol = ((lslot ^ lr) * 8);

  for (int kt = 0; kt < K; kt += 64) {
    __syncthreads();
#pragma unroll
    for (int i = 0; i < 4; ++i) {
      int ch = i * 4 + w;
      int row = ch * 8 + lr;
      gload_lds16(gA + (size_t)row * K + kt + scol, &lA[ch * 512]);
      gload_lds16(gB + (size_t)row * K + kt + scol, &lB[ch * 512]);
    }
    __syncthreads();
#pragma unroll
    for (int kk = 0; kk < 2; ++kk) {
      short8 af[4], bfr[4];
#pragma unroll
      for (int mf = 0; mf < 4; ++mf) {
        int row = wm * 64 + mf * 16 + li;
        af[mf] = *(const short8*)&lA[row * 64 + (((kk * 4 + lg)) ^ (row & 7)) * 8];
      }
#pragma unroll
      for (int nf = 0; nf < 4; ++nf) {
        int row = wn * 64 + nf * 16 + li;
        bfr[nf] = *(const short8*)&lB[row * 64 + (((kk * 4 + lg)) ^ (row & 7)) * 8];
      }
#pragma unroll
      for (int mf = 0; mf < 4; ++mf)
#pragma unroll
        for (int nf = 0; nf < 4; ++nf)
          acc[mf][nf] = __builtin_amdgcn_mfma_f32_16x16x32_bf16(af[mf], bfr[nf], acc[mf][nf], 0, 0, 0);
    }
  }
  if (EPI == 0) {
#pragma unroll
    for (int mf = 0; mf < 4; ++mf) {
      int mg0 = tm * 128 + wm * 64 + mf * 16 + lg * 4;
#pragma unroll
      for (int nf = 0; nf < 4; ++nf) {
        int ng = tn * 128 + wn * 64 + nf * 16 + li;
#pragma unroll
        for (int r = 0; r < 4; ++r)
          Cf[(size_t)(mg0 + r) * 1024 + ng] = acc[mf][nf][r];
      }
    }
  } else {
    int which = tn >> 3;                 // 0=q 1=k 2=v (128-col tiles, 8 per matrix)
    int h = (tn & 7) * 2 + wn;           // head
    int b = tm >> 4;                     // 128 | 2048: block never straddles batches
    if (which < 2) {
      float scale = (which == 0) ? 0.125f * 1.44269504088896f : 1.0f;
      u16* qk0 = qb + (((size_t)b * HQ + h) * SQ << 6);
      u16* kb0 = kb + ((size_t)b * HQ + h) * (64 * 2048);
#pragma unroll
      for (int mf = 0; mf < 4; ++mf) {
#pragma unroll
        for (int r = 0; r < 4; ++r) {
          int s = (tm * 128 + wm * 64 + mf * 16 + lg * 4 + r) & 2047;
#pragma unroll
          for (int nf2 = 0; nf2 < 2; ++nf2) {
            int dp = nf2 * 16 + li;      // 0..31; rope pair (dp, dp+32)
            float2 cs = *(const float2*)&tab[(s * 32 + dp) * 2];
            float a = acc[mf][nf2][r];
            float bb = acc[mf][nf2 + 2][r];
            float lo = (a * cs.x - bb * cs.y) * scale;
            float hi2 = (bb * cs.x + a * cs.y) * scale;
            if (which == 0) {
              u16* dst = qk0 + ((size_t)s << 6);
              dst[dp] = f2bf(lo);
              dst[dp + 32] = f2bf(hi2);
            } else {
              // tiled K: [kt][slot=d>>3][j=s&31][e=d&7]
              u16* dst = kb0 + (s >> 5) * 2048 + (s & 31) * 8;
              dst[(dp >> 3) * 256 + (dp & 7)] = f2bf(lo);
              dst[(dp >> 3) * 256 + 1024 + (dp & 7)] = f2bf(hi2);  // d+32 -> slot+4
            }
          }
        }
      }
    } else {
      // tiled V: [kt][slot=k>>3][d][e=k&7]; pack 4 consecutive kk -> one 8B store
#pragma unroll
      for (int mf = 0; mf < 4; ++mf) {
        int s0 = (tm * 128 + wm * 64 + mf * 16 + lg * 4) & 2047;
        int kt = s0 >> 5, kk0 = s0 & 31;
        size_t tb = (((size_t)(b * HQ + h) * 64 + kt) * 2048) + (kk0 >> 3) * 512 + (kk0 & 7);
#pragma unroll
        for (int nf = 0; nf < 4; ++nf) {
          int d = nf * 16 + li;
          u32 w0 = pkbf(acc[mf][nf][0], acc[mf][nf][1]);
          u32 w1 = pkbf(acc[mf][nf][2], acc[mf][nf][3]);
          *(u32x2*)&vTs[tb + d * 8] = (u32x2){w0, w1};
        }
      }
    }
  }
}

// ---------------- flash attention v7 (83us verified) + tiled bank-optimal K/V LDS ----------------
// Block = 4 waves on q-tiles {qsup*4 .. qsup*4+3} of ONE bh. Per k-tile the block stages
// K (4KB) + V^T (4KB) via linear global_load_lds from the pre-tiled kbuf/vTs layouts,
// double-buffered, one barrier per tile. Every ds_read_b128 has lanes j=0..31 reading
// CONSECUTIVE 16B slots -> bank-optimal, no XOR swizzles.
__global__ __launch_bounds__(256) void k_flash7(const u16* __restrict__ Q, const u16* __restrict__ Kb,
                                                const u16* __restrict__ VTs, const int* __restrict__ mask,
                                                const u64* __restrict__ mbits, u16* __restrict__ O) {
  __shared__ alignas(16) u16 Kl[2][2048];
  __shared__ alignas(16) u16 Vl[2][2048];
  int bid = blockIdx.x;
  int bh = bid & 63;
  int u = bid >> 6, v = u & 3, k4 = u >> 2;
  int qsup = (k4 == 0) ? v : (k4 == 1) ? 7 - v : (k4 == 2) ? 8 + v : 15 - v;
  int tid = threadIdx.x, w = tid >> 6, l = tid & 63;
  int j = l & 31, hi = l >> 5;
  int myqt = qsup * 4 + w;
  int nt = qsup * 4 + 4;
  int b = bh >> 4, h = bh & 15;
  const int* mp = mask + b * SQ + 4 * hi;
  u64 mb = mbits[b];

  // staging sources: tiled layouts are linear per 4KB tile
  const u16* Kg0 = Kb + (size_t)bh * (64 * 2048) + tid * 8;   // + kt*2048
  const u16* Vg0 = VTs + (size_t)bh * (64 * 2048) + tid * 8;  // + kt*2048
  u16* KlB = &Kl[0][(size_t)w * 512];  // wave-uniform dest bases (buffer toggled by +2048 u16)
  u16* VlB = &Vl[0][(size_t)w * 512];

  // Q fragments (B operand)
  int qbase = myqt * 32;
  const u16* qp = Q + ((size_t)bh * SQ + qbase + j) * 64 + hi * 8;
  short8 qf[4];
#pragma unroll
  for (int kb = 0; kb < 4; ++kb) qf[kb] = *(const short8*)(qp + kb * 16);

  f32x16 o0, o1;
#pragma unroll
  for (int i = 0; i < 16; ++i) { o0[i] = 0.f; o1[i] = 0.f; }
  float mrun = -INFINITY, lrun = 0.f;

  // prologue: stage tile 0 into buffer 0
  gload_lds16(Kg0, KlB);
  gload_lds16(Vg0, VlB);
  __syncthreads();

  for (int kt = 0; kt < nt; ++kt) {
    int cur = kt & 1;
    if (kt + 1 < nt) {  // stage next tile into other buffer
      gload_lds16(Kg0 + (size_t)(kt + 1) * 2048, KlB + (cur ^ 1) * 2048);
      gload_lds16(Vg0 + (size_t)(kt + 1) * 2048, VlB + (cur ^ 1) * 2048);
    }

    if (kt <= myqt) {
      const u16* Kc = Kl[cur];
      const u16* Vc = Vl[cur];

      // K fragment: tiled [slot=hi+2kb][j][8] -> consecutive 16B across lanes
      short8 kcf[4];
#pragma unroll
      for (int kb = 0; kb < 4; ++kb)
        kcf[kb] = *(const short8*)&Kc[(hi + 2 * kb) * 256 + j * 8];

      f32x16 s;
#pragma unroll
      for (int i = 0; i < 16; ++i) s[i] = 0.f;
      __builtin_amdgcn_s_setprio(1);
#pragma unroll
      for (int kb = 0; kb < 4; ++kb)
        s = __builtin_amdgcn_mfma_f32_32x32x16_bf16(kcf[kb], qf[kb], s, 0, 0, 0);
      __builtin_amdgcn_s_setprio(0);

      // V fragments: tiled [slot][d][8]
      short8 va0 = *(const short8*)&Vc[hi * 512 + j * 8];
      short8 va1 = *(const short8*)&Vc[(hi + 2) * 512 + j * 8];
      short8 vb0 = *(const short8*)&Vc[hi * 512 + (j + 32) * 8];
      short8 vb1 = *(const short8*)&Vc[(hi + 2) * 512 + (j + 32) * 8];

      // pad mask: only when this 32-chunk has zeros (never in this harness)
      if (!((mb >> kt) & 1ull)) {
#pragma unroll
        for (int rq = 0; rq < 4; ++rq) {
          int4 mv = *(const int4*)(mp + kt * 32 + 8 * rq);
          if (!mv.x) s[4 * rq + 0] = -INFINITY;
          if (!mv.y) s[4 * rq + 1] = -INFINITY;
          if (!mv.z) s[4 * rq + 2] = -INFINITY;
          if (!mv.w) s[4 * rq + 3] = -INFINITY;
        }
      }
      // causal: diagonal tile masks k>q
      if (kt == myqt) {
#pragma unroll
        for (int rq = 0; rq < 4; ++rq)
#pragma unroll
          for (int t = 0; t < 4; ++t)
            if (8 * rq + 4 * hi + t > j) s[4 * rq + t] = -INFINITY;
      }

      // online softmax in log2 domain, fully in-register
      float t0 = fmaxf(fmaxf(fmaxf(s[0], s[1]), fmaxf(s[2], s[3])),
                       fmaxf(fmaxf(s[4], s[5]), fmaxf(s[6], s[7])));
      t0 = fmaxf(t0, fmaxf(fmaxf(fmaxf(s[8], s[9]), fmaxf(s[10], s[11])),
                           fmaxf(fmaxf(s[12], s[13]), fmaxf(s[14], s[15]))));
      if (!__all(t0 <= mrun + 8.0f)) {  // defer-max (T13)
        float tm2 = xmax32(t0);
        float mn = fmaxf(fmaxf(mrun, tm2), -1e30f);
        float alpha = fexp2(mrun - mn);
        mrun = mn;
        lrun *= alpha;
#pragma unroll
        for (int i = 0; i < 16; ++i) { o0[i] *= alpha; o1[i] *= alpha; }
      }
      float ts = 0.f;
#pragma unroll
      for (int i = 0; i < 16; ++i) {
        float pv = fexp2(s[i] - mrun);
        s[i] = pv;
        ts += pv;
      }
      lrun += ts;

      // pack P^T into B fragments: cvt_pk pairs + one cross-half shfl per word-pair
      u32 pa[4], pb[4];
#pragma unroll
      for (int q2 = 0; q2 < 4; ++q2) {
        pa[q2] = pkbf(s[4 * q2 + 0], s[4 * q2 + 1]);
        pb[q2] = pkbf(s[4 * q2 + 2], s[4 * q2 + 3]);
      }
      u32 ya01 = xword(hi ? pa[0] : pa[1]);
      u32 yb01 = xword(hi ? pb[0] : pb[1]);
      u32 ya23 = xword(hi ? pa[2] : pa[3]);
      u32 yb23 = xword(hi ? pb[2] : pb[3]);
      union { short8 s8; u32 wd[4]; } f0, f1;
      f0.wd[0] = hi ? ya01 : pa[0];
      f0.wd[1] = hi ? yb01 : pb[0];
      f0.wd[2] = hi ? pa[1] : ya01;
      f0.wd[3] = hi ? pb[1] : yb01;
      f1.wd[0] = hi ? ya23 : pa[2];
      f1.wd[1] = hi ? yb23 : pb[2];
      f1.wd[2] = hi ? pa[3] : ya23;
      f1.wd[3] = hi ? pb[3] : yb23;

      // PV: O^T += V^T(frag A) x P^T(frag B)
      __builtin_amdgcn_s_setprio(1);
      o0 = __builtin_amdgcn_mfma_f32_32x32x16_bf16(va0, f0.s8, o0, 0, 0, 0);
      o0 = __builtin_amdgcn_mfma_f32_32x32x16_bf16(va1, f1.s8, o0, 0, 0, 0);
      o1 = __builtin_amdgcn_mfma_f32_32x32x16_bf16(vb0, f0.s8, o1, 0, 0, 0);
      o1 = __builtin_amdgcn_mfma_f32_32x32x16_bf16(vb1, f1.s8, o1, 0, 0, 0);
      __builtin_amdgcn_s_setprio(0);
    }

    __syncthreads();  // drains vmem (next stage) + all waves done reading cur
  }

  // epilogue: merge the two halves' lrun, store q rows
  float lfull = xsum32(lrun);
  float inv = 1.0f / lfull;
  u16* ob = O + ((size_t)b * SQ + qbase + j) * DQ + h * 64 + 4 * hi;
#pragma unroll
  for (int q2 = 0; q2 < 4; ++q2) {
#pragma unroll
    for (int e = 0; e < 2; ++e) {
      *(u32*)(ob + 8 * q2 + 2 * e) = pkbf(o0[4 * q2 + 2 * e] * inv, o0[4 * q2 + 2 * e + 1] * inv);
      *(u32*)(ob + 32 + 8 * q2 + 2 * e) = pkbf(o1[4 * q2 + 2 * e] * inv, o1[4 * q2 + 2 * e + 1] * inv);
    }
  }
}

extern "C" void kernel_launch(void* const* d_in, const int* in_sizes, int n_in,
                              void* d_out, int out_size, void* d_ws, size_t ws_size,
                              hipStream_t stream) {
  const float* x = (const float*)d_in[0];
  const int* mask = (const int*)d_in[1];
  const float* wqkv = (const float*)d_in[2];
  const float* wout = (const float*)d_in[3];
  float* out = (float*)d_out;
  char* ws = (char*)d_ws;

  u16* xb    = (u16*)(ws + 0);           // 16 MB
  u16* wqkvT = (u16*)(ws + 16777216);    // 6 MB  [3072][1024]
  u16* woutT = (u16*)(ws + 23068672);    // 2 MB  [1024][1024]
  u16* qbuf  = (u16*)(ws + 25165824);    // 16 MB [bh][S][64]
  u16* kbuf  = (u16*)(ws + 41943040);    // 16 MB [bh][64 kt][8 slot][32 j][8] tiled
  u16* vTs   = (u16*)(ws + 75497472);    // 16 MB [bh][64 kt][4 slot][64 d][8] tiled
  u16* attnb = (u16*)(ws + 92274688);    // 16 MB [B*S][1024]
  float* tab = (float*)(ws + 109051904); // 512 KB
  u64* mbits = (u64*)(ws + 109576192);   // 32 B

  k_prep<<<12545, 256, 0, stream>>>(x, xb, wqkv, wqkvT, wout, woutT, tab, mask, mbits);
  k_gemm<1><<<1536, 256, 0, stream>>>(xb, wqkvT, nullptr, qbuf, kbuf, vTs, tab, 1024);
  k_flash7<<<1024, 256, 0, stream>>>(qbuf, kbuf, vTs, mask, mbits, attnb);
  k_gemm<0><<<512, 256, 0, stream>>>(attnb, woutT, out, nullptr, nullptr, nullptr, nullptr, 1024);
}

// Round 17
// 185.440 us; speedup vs baseline: 1.3815x; 1.0018x over previous
//
#include <hip/hip_runtime.h>

#define BQ 4
#define SQ 2048
#define DQ 1024
#define HQ 16
#define BHQ 64

typedef __attribute__((ext_vector_type(8))) short short8;
typedef __attribute__((ext_vector_type(4))) float f32x4;
typedef __attribute__((ext_vector_type(16))) float f32x16;
typedef __attribute__((ext_vector_type(2))) unsigned int u32x2;
typedef unsigned short u16;
typedef unsigned int u32;
typedef unsigned long long u64;

__device__ __forceinline__ u16 f2bf(float f) {
  u32 u = __float_as_uint(f);
  u32 r = u + 0x7fffu + ((u >> 16) & 1u);
  return (u16)(r >> 16);
}
__device__ __forceinline__ float bf2f(u16 h) {
  return __uint_as_float(((u32)h) << 16);
}

// packed f32x2 -> bf16x2 (RNE), one instruction
__device__ __forceinline__ u32 pkbf(float lo, float hi_) {
  u32 r;
  asm("v_cvt_pk_bf16_f32 %0, %1, %2" : "=v"(r) : "v"(lo), "v"(hi_));
  return r;
}
// raw v_exp_f32: computes 2^x (input already in log2 domain)
__device__ __forceinline__ float fexp2(float x) {
  float r;
  asm("v_exp_f32 %0, %1" : "=v"(r) : "v"(x));
  return r;
}
// cross-half exchange via shfl (known-correct)
__device__ __forceinline__ float xmax32(float x) { return fmaxf(x, __shfl_xor(x, 32)); }
__device__ __forceinline__ float xsum32(float x) { return x + __shfl_xor(x, 32); }
__device__ __forceinline__ u32 xword(u32 send) { return (u32)__shfl_xor((int)send, 32); }

// async global->LDS, 16B per lane. LDS dest must be wave-uniform; HW adds lane*16.
__device__ __forceinline__ void gload_lds16(const void* g, void* l) {
  __builtin_amdgcn_global_load_lds(
      (const __attribute__((address_space(1))) u32*)(unsigned long long)g,
      (__attribute__((address_space(3))) u32*)(u32)(unsigned long long)l,
      16, 0, 0);
}

// ---------------- fused prep: cvt x | transpose wqkv | transpose wout | rope tab | mflags ----------------
__device__ __forceinline__ void transpose_body(const float* __restrict__ in, u16* __restrict__ out,
                                               int R, int C, int bx, int by, int tid) {
  __shared__ float t[32][33];
  int c0 = bx * 32, r0 = by * 32;
  int tx = tid & 31, ty = tid >> 5;
  for (int rr = ty; rr < 32; rr += 8)
    t[rr][tx] = in[(size_t)(r0 + rr) * C + c0 + tx];
  __syncthreads();
  for (int rr = ty; rr < 32; rr += 8)
    out[(size_t)(c0 + rr) * R + r0 + tx] = f2bf(t[tx][rr]);
}

__global__ __launch_bounds__(256) void k_prep(const float* __restrict__ x, u16* __restrict__ xb,
                                              const float* __restrict__ wqkv, u16* __restrict__ wqkvT,
                                              const float* __restrict__ wout, u16* __restrict__ woutT,
                                              float* __restrict__ tab, const int* __restrict__ mask,
                                              u64* __restrict__ mbits) {
  int bid = blockIdx.x, tid = threadIdx.x;
  if (bid < 8192) {                       // cvt x -> bf16 (2M float4)
    int i = bid * 256 + tid;
    float4 v = ((const float4*)x)[i];
    ushort4 o;
    o.x = f2bf(v.x); o.y = f2bf(v.y); o.z = f2bf(v.z); o.w = f2bf(v.w);
    ((ushort4*)xb)[i] = o;
  } else if (bid < 11264) {               // transpose wqkv [1024][3072] -> [3072][1024]
    int t = bid - 8192;
    transpose_body(wqkv, wqkvT, 1024, 3072, t % 96, t / 96, tid);
  } else if (bid < 12288) {               // transpose wout [1024][1024]
    int t = bid - 11264;
    transpose_body(wout, woutT, 1024, 1024, t % 32, t / 32, tid);
  } else if (bid < 12544) {               // rope cos/sin table [S][32][2]
    int i = (bid - 12288) * 256 + tid;
    int s = i >> 5, dp = i & 31;
    float invf = expf(-0.28782313662425576f * (float)dp);
    float ang = (float)s * invf;
    tab[i * 2] = cosf(ang);
    tab[i * 2 + 1] = sinf(ang);
  } else {                                // mask bitmask (1 block: wave=batch, lane=chunk)
    int b = tid >> 6, c = tid & 63;
    int all1 = 1;
    for (int i = 0; i < 32; ++i) all1 &= (mask[b * SQ + c * 32 + i] != 0) ? 1 : 0;
    u64 m = __ballot(all1);
    if (c == 0) mbits[b] = m;
  }
}

// ---------------- GEMM: C[M,N] = A[M,K](bf16) @ Bt[N,K]^T(bf16) ----------------
// BK=64, K-swizzled LDS. 1D grid with XCD-chunked (tm,tn) map: xcd=bid&7 owns
// tm in [xcd*8, xcd*8+8) (2MB of A = L2-resident) across all tn epochs.
// EPI 0: write f32 C row-major. EPI 1 (QKV): fused RoPE q/k + tiled K/V scatter:
//   kbuf tiled [bh][kt][8 slot=d>>3][32 j=s&31][8 e]   (bank-optimal flash reads)
//   vTs  tiled [bh][kt][4 slot=k>>3][64 d][8 e]
template <int EPI>
__global__ __launch_bounds__(256) void k_gemm(const u16* __restrict__ A, const u16* __restrict__ Bt,
                                              float* __restrict__ Cf, u16* __restrict__ qb,
                                              u16* __restrict__ kb, u16* __restrict__ vTs,
                                              const float* __restrict__ tab, int K) {
  __shared__ u16 lA[128 * 64];
  __shared__ u16 lB[128 * 64];
  int bid = blockIdx.x;
  int i_ = bid >> 3;
  int tm = (bid & 7) * 8 + (i_ & 7);
  int tn = i_ >> 3;
  int tid = threadIdx.x, w = tid >> 6, l = tid & 63;
  int wm = w >> 1, wn = w & 1;
  int li = l & 15, lg = l >> 4;
  const u16* gA = A + (size_t)tm * 128 * K;
  const u16* gB = Bt + (size_t)tn * 128 * K;
  f32x4 acc[4][4];
#pragma unroll
  for (int i = 0; i < 4; i++)
#pragma unroll
    for (int j = 0; j < 4; j++) acc[i][j] = (f32x4){0.f, 0.f, 0.f, 0.f};

  int lr = l >> 3, lslot = l & 7;
  int scol = ((lslot ^ lr) * 8);

  for (int kt = 0; kt < K; kt += 64) {
    __syncthreads();
#pragma unroll
    for (int i = 0; i < 4; ++i) {
      int ch = i * 4 + w;
      int row = ch * 8 + lr;
      gload_lds16(gA + (size_t)row * K + kt + scol, &lA[ch * 512]);
      gload_lds16(gB + (size_t)row * K + kt + scol, &lB[ch * 512]);
    }
    __syncthreads();
#pragma unroll
    for (int kk = 0; kk < 2; ++kk) {
      short8 af[4], bfr[4];
#pragma unroll
      for (int mf = 0; mf < 4; ++mf) {
        int row = wm * 64 + mf * 16 + li;
        af[mf] = *(const short8*)&lA[row * 64 + (((kk * 4 + lg)) ^ (row & 7)) * 8];
      }
#pragma unroll
      for (int nf = 0; nf < 4; ++nf) {
        int row = wn * 64 + nf * 16 + li;
        bfr[nf] = *(const short8*)&lB[row * 64 + (((kk * 4 + lg)) ^ (row & 7)) * 8];
      }
#pragma unroll
      for (int mf = 0; mf < 4; ++mf)
#pragma unroll
        for (int nf = 0; nf < 4; ++nf)
          acc[mf][nf] = __builtin_amdgcn_mfma_f32_16x16x32_bf16(af[mf], bfr[nf], acc[mf][nf], 0, 0, 0);
    }
  }
  if (EPI == 0) {
#pragma unroll
    for (int mf = 0; mf < 4; ++mf) {
      int mg0 = tm * 128 + wm * 64 + mf * 16 + lg * 4;
#pragma unroll
      for (int nf = 0; nf < 4; ++nf) {
        int ng = tn * 128 + wn * 64 + nf * 16 + li;
#pragma unroll
        for (int r = 0; r < 4; ++r)
          Cf[(size_t)(mg0 + r) * 1024 + ng] = acc[mf][nf][r];
      }
    }
  } else {
    int which = tn >> 3;                 // 0=q 1=k 2=v (128-col tiles, 8 per matrix)
    int h = (tn & 7) * 2 + wn;           // head
    int b = tm >> 4;                     // 128 | 2048: block never straddles batches
    if (which < 2) {
      float scale = (which == 0) ? 0.125f * 1.44269504088896f : 1.0f;
      u16* qk0 = qb + (((size_t)b * HQ + h) * SQ << 6);
      u16* kb0 = kb + ((size_t)b * HQ + h) * (64 * 2048);
#pragma unroll
      for (int mf = 0; mf < 4; ++mf) {
#pragma unroll
        for (int r = 0; r < 4; ++r) {
          int s = (tm * 128 + wm * 64 + mf * 16 + lg * 4 + r) & 2047;
#pragma unroll
          for (int nf2 = 0; nf2 < 2; ++nf2) {
            int dp = nf2 * 16 + li;      // 0..31; rope pair (dp, dp+32)
            float2 cs = *(const float2*)&tab[(s * 32 + dp) * 2];
            float a = acc[mf][nf2][r];
            float bb = acc[mf][nf2 + 2][r];
            float lo = (a * cs.x - bb * cs.y) * scale;
            float hi2 = (bb * cs.x + a * cs.y) * scale;
            if (which == 0) {
              u16* dst = qk0 + ((size_t)s << 6);
              dst[dp] = f2bf(lo);
              dst[dp + 32] = f2bf(hi2);
            } else {
              // tiled K: [kt][slot=d>>3][j=s&31][e=d&7]
              u16* dst = kb0 + (s >> 5) * 2048 + (s & 31) * 8;
              dst[(dp >> 3) * 256 + (dp & 7)] = f2bf(lo);
              dst[(dp >> 3) * 256 + 1024 + (dp & 7)] = f2bf(hi2);  // d+32 -> slot+4
            }
          }
        }
      }
    } else {
      // tiled V: [kt][slot=k>>3][d][e=k&7]; pack 4 consecutive kk -> one 8B store
#pragma unroll
      for (int mf = 0; mf < 4; ++mf) {
        int s0 = (tm * 128 + wm * 64 + mf * 16 + lg * 4) & 2047;
        int kt = s0 >> 5, kk0 = s0 & 31;
        size_t tb = (((size_t)(b * HQ + h) * 64 + kt) * 2048) + (kk0 >> 3) * 512 + (kk0 & 7);
#pragma unroll
        for (int nf = 0; nf < 4; ++nf) {
          int d = nf * 16 + li;
          u32 w0 = pkbf(acc[mf][nf][0], acc[mf][nf][1]);
          u32 w1 = pkbf(acc[mf][nf][2], acc[mf][nf][3]);
          *(u32x2*)&vTs[tb + d * 8] = (u32x2){w0, w1};
        }
      }
    }
  }
}

// ---------------- flash v12: flash7 body, TWO k-tiles per barrier phase ----------------
// Same 1024-block grid / qsup quads / tiled bank-optimal LDS as the verified flash7.
// Per phase: stage 2 K-tiles + 2 V-tiles (16KB) into the other buffer, then run the
// flash7 per-tile body verbatim for sub-tiles 2ph and 2ph+1 (bit-identical math),
// ONE barrier per phase (barriers halved: 136 -> 68 per CU).
__global__ __launch_bounds__(256) void k_flash12(const u16* __restrict__ Q, const u16* __restrict__ Kb,
                                                 const u16* __restrict__ VTs, const int* __restrict__ mask,
                                                 const u64* __restrict__ mbits, u16* __restrict__ O) {
  __shared__ alignas(16) u16 Kl[2][4096];
  __shared__ alignas(16) u16 Vl[2][4096];
  int bid = blockIdx.x;
  int bh = bid & 63;
  int u = bid >> 6, v = u & 3, k4 = u >> 2;
  int qsup = (k4 == 0) ? v : (k4 == 1) ? 7 - v : (k4 == 2) ? 8 + v : 15 - v;
  int tid = threadIdx.x, w = tid >> 6, l = tid & 63;
  int j = l & 31, hi = l >> 5;
  int myqt = qsup * 4 + w;
  int P = 2 * qsup + 2;  // phases; tiles 0..4qsup+3
  int b = bh >> 4, h = bh & 15;
  const int* mp = mask + b * SQ + 4 * hi;
  u64 mb = mbits[b];

  // staging sources: tiled layouts are linear per 4KB tile
  const u16* Kg0 = Kb + (size_t)bh * (64 * 2048) + tid * 8;   // + kt*2048
  const u16* Vg0 = VTs + (size_t)bh * (64 * 2048) + tid * 8;  // + kt*2048
  u16* KlB = &Kl[0][(size_t)w * 512];  // wave-uniform dest bases (+sub*2048, +buf*4096 u16)
  u16* VlB = &Vl[0][(size_t)w * 512];

  // Q fragments (B operand)
  int qbase = myqt * 32;
  const u16* qp = Q + ((size_t)bh * SQ + qbase + j) * 64 + hi * 8;
  short8 qf[4];
#pragma unroll
  for (int kb = 0; kb < 4; ++kb) qf[kb] = *(const short8*)(qp + kb * 16);

  f32x16 o0, o1;
#pragma unroll
  for (int i = 0; i < 16; ++i) { o0[i] = 0.f; o1[i] = 0.f; }
  float mrun = -INFINITY, lrun = 0.f;

  // prologue: stage tiles 0,1 into buffer 0
  gload_lds16(Kg0, KlB);
  gload_lds16(Kg0 + 2048, KlB + 2048);
  gload_lds16(Vg0, VlB);
  gload_lds16(Vg0 + 2048, VlB + 2048);
  __syncthreads();

  for (int ph = 0; ph < P; ++ph) {
    int cur = ph & 1;
    if (ph + 1 < P) {  // stage next 2 tiles into other buffer
      const u16* kg = Kg0 + (size_t)(2 * ph + 2) * 2048;
      const u16* vg = Vg0 + (size_t)(2 * ph + 2) * 2048;
      u16* kd = KlB + (cur ^ 1) * 4096;
      u16* vd = VlB + (cur ^ 1) * 4096;
      gload_lds16(kg, kd);
      gload_lds16(kg + 2048, kd + 2048);
      gload_lds16(vg, vd);
      gload_lds16(vg + 2048, vd + 2048);
    }

#pragma unroll
    for (int sub = 0; sub < 2; ++sub) {
      int kt = 2 * ph + sub;
      if (kt <= myqt) {
        const u16* Kc = &Kl[cur][sub * 2048];
        const u16* Vc = &Vl[cur][sub * 2048];

        // K fragment: tiled [slot=hi+2kb][j][8] -> consecutive 16B across lanes
        short8 kcf[4];
#pragma unroll
        for (int kb = 0; kb < 4; ++kb)
          kcf[kb] = *(const short8*)&Kc[(hi + 2 * kb) * 256 + j * 8];

        f32x16 s;
#pragma unroll
        for (int i = 0; i < 16; ++i) s[i] = 0.f;
        __builtin_amdgcn_s_setprio(1);
#pragma unroll
        for (int kb = 0; kb < 4; ++kb)
          s = __builtin_amdgcn_mfma_f32_32x32x16_bf16(kcf[kb], qf[kb], s, 0, 0, 0);
        __builtin_amdgcn_s_setprio(0);

        // V fragments: tiled [slot][d][8]
        short8 va0 = *(const short8*)&Vc[hi * 512 + j * 8];
        short8 va1 = *(const short8*)&Vc[(hi + 2) * 512 + j * 8];
        short8 vb0 = *(const short8*)&Vc[hi * 512 + (j + 32) * 8];
        short8 vb1 = *(const short8*)&Vc[(hi + 2) * 512 + (j + 32) * 8];

        // pad mask: only when this 32-chunk has zeros (never in this harness)
        if (!((mb >> kt) & 1ull)) {
#pragma unroll
          for (int rq = 0; rq < 4; ++rq) {
            int4 mv = *(const int4*)(mp + kt * 32 + 8 * rq);
            if (!mv.x) s[4 * rq + 0] = -INFINITY;
            if (!mv.y) s[4 * rq + 1] = -INFINITY;
            if (!mv.z) s[4 * rq + 2] = -INFINITY;
            if (!mv.w) s[4 * rq + 3] = -INFINITY;
          }
        }
        // causal: diagonal tile masks k>q
        if (kt == myqt) {
#pragma unroll
          for (int rq = 0; rq < 4; ++rq)
#pragma unroll
            for (int t = 0; t < 4; ++t)
              if (8 * rq + 4 * hi + t > j) s[4 * rq + t] = -INFINITY;
        }

        // online softmax in log2 domain, fully in-register
        float t0 = fmaxf(fmaxf(fmaxf(s[0], s[1]), fmaxf(s[2], s[3])),
                         fmaxf(fmaxf(s[4], s[5]), fmaxf(s[6], s[7])));
        t0 = fmaxf(t0, fmaxf(fmaxf(fmaxf(s[8], s[9]), fmaxf(s[10], s[11])),
                             fmaxf(fmaxf(s[12], s[13]), fmaxf(s[14], s[15]))));
        if (!__all(t0 <= mrun + 8.0f)) {  // defer-max (T13)
          float tm2 = xmax32(t0);
          float mn = fmaxf(fmaxf(mrun, tm2), -1e30f);
          float alpha = fexp2(mrun - mn);
          mrun = mn;
          lrun *= alpha;
#pragma unroll
          for (int i = 0; i < 16; ++i) { o0[i] *= alpha; o1[i] *= alpha; }
        }
        float ts = 0.f;
#pragma unroll
        for (int i = 0; i < 16; ++i) {
          float pv = fexp2(s[i] - mrun);
          s[i] = pv;
          ts += pv;
        }
        lrun += ts;

        // pack P^T into B fragments: cvt_pk pairs + one cross-half shfl per word-pair
        u32 pa[4], pb[4];
#pragma unroll
        for (int q2 = 0; q2 < 4; ++q2) {
          pa[q2] = pkbf(s[4 * q2 + 0], s[4 * q2 + 1]);
          pb[q2] = pkbf(s[4 * q2 + 2], s[4 * q2 + 3]);
        }
        u32 ya01 = xword(hi ? pa[0] : pa[1]);
        u32 yb01 = xword(hi ? pb[0] : pb[1]);
        u32 ya23 = xword(hi ? pa[2] : pa[3]);
        u32 yb23 = xword(hi ? pb[2] : pb[3]);
        union { short8 s8; u32 wd[4]; } f0, f1;
        f0.wd[0] = hi ? ya01 : pa[0];
        f0.wd[1] = hi ? yb01 : pb[0];
        f0.wd[2] = hi ? pa[1] : ya01;
        f0.wd[3] = hi ? pb[1] : yb01;
        f1.wd[0] = hi ? ya23 : pa[2];
        f1.wd[1] = hi ? yb23 : pb[2];
        f1.wd[2] = hi ? pa[3] : ya23;
        f1.wd[3] = hi ? pb[3] : yb23;

        // PV: O^T += V^T(frag A) x P^T(frag B)
        __builtin_amdgcn_s_setprio(1);
        o0 = __builtin_amdgcn_mfma_f32_32x32x16_bf16(va0, f0.s8, o0, 0, 0, 0);
        o0 = __builtin_amdgcn_mfma_f32_32x32x16_bf16(va1, f1.s8, o0, 0, 0, 0);
        o1 = __builtin_amdgcn_mfma_f32_32x32x16_bf16(vb0, f0.s8, o1, 0, 0, 0);
        o1 = __builtin_amdgcn_mfma_f32_32x32x16_bf16(vb1, f1.s8, o1, 0, 0, 0);
        __builtin_amdgcn_s_setprio(0);
      }
    }

    __syncthreads();  // drains vmem (next stage) + all waves done reading cur
  }

  // epilogue: merge the two halves' lrun, store q rows
  float lfull = xsum32(lrun);
  float inv = 1.0f / lfull;
  u16* ob = O + ((size_t)b * SQ + qbase + j) * DQ + h * 64 + 4 * hi;
#pragma unroll
  for (int q2 = 0; q2 < 4; ++q2) {
#pragma unroll
    for (int e = 0; e < 2; ++e) {
      *(u32*)(ob + 8 * q2 + 2 * e) = pkbf(o0[4 * q2 + 2 * e] * inv, o0[4 * q2 + 2 * e + 1] * inv);
      *(u32*)(ob + 32 + 8 * q2 + 2 * e) = pkbf(o1[4 * q2 + 2 * e] * inv, o1[4 * q2 + 2 * e + 1] * inv);
    }
  }
}

extern "C" void kernel_launch(void* const* d_in, const int* in_sizes, int n_in,
                              void* d_out, int out_size, void* d_ws, size_t ws_size,
                              hipStream_t stream) {
  const float* x = (const float*)d_in[0];
  const int* mask = (const int*)d_in[1];
  const float* wqkv = (const float*)d_in[2];
  const float* wout = (const float*)d_in[3];
  float* out = (float*)d_out;
  char* ws = (char*)d_ws;

  u16* xb    = (u16*)(ws + 0);           // 16 MB
  u16* wqkvT = (u16*)(ws + 16777216);    // 6 MB  [3072][1024]
  u16* woutT = (u16*)(ws + 23068672);    // 2 MB  [1024][1024]
  u16* qbuf  = (u16*)(ws + 25165824);    // 16 MB [bh][S][64]
  u16* kbuf  = (u16*)(ws + 41943040);    // 16 MB [bh][64 kt][8 slot][32 j][8] tiled
  u16* vTs   = (u16*)(ws + 75497472);    // 16 MB [bh][64 kt][4 slot][64 d][8] tiled
  u16* attnb = (u16*)(ws + 92274688);    // 16 MB [B*S][1024]
  float* tab = (float*)(ws + 109051904); // 512 KB
  u64* mbits = (u64*)(ws + 109576192);   // 32 B

  k_prep<<<12545, 256, 0, stream>>>(x, xb, wqkv, wqkvT, wout, woutT, tab, mask, mbits);
  k_gemm<1><<<1536, 256, 0, stream>>>(xb, wqkvT, nullptr, qbuf, kbuf, vTs, tab, 1024);
  k_flash12<<<1024, 256, 0, stream>>>(qbuf, kbuf, vTs, mask, mbits, attnb);
  k_gemm<0><<<512, 256, 0, stream>>>(attnb, woutT, out, nullptr, nullptr, nullptr, nullptr, 1024);
}